// Round 7
// baseline (246.795 us; speedup 1.0000x reference)
//
#include <hip/hip_runtime.h>
#include <math.h>

// Problem constants
#define NPIX  36864            // 192*192
#define PI2   6.28318530717958647692f

// Workspace layout (bytes)
#define TW_OFF    0            // 192 float2 twiddles e^{+2pi i n/192}
#define PCA_OFF   1536         // 576 float4 {a1, lf0, a2, th}
#define PCB_OFF   10752        // 576 float2 {fr, lsc}
#define W1F4_OFF  15360        // 64 float4 {w1[0..2], b1}
#define W2B_OFF   16384        // MFMA B-frags bf16 hi/lo, t-major (r6): 49152 B
#define BN_OFF    65536        // 192 scale + 192 shift
#define IDX_OFF   67072        // 192*2 ints shifted intervals [o][i]{lo,hi}
#define M2_OFF    68608        // 64*64 M2 + 64 m1 floats (zeroed)
#define T1_OFF    85248        // split: E1 stage-1 twiddle A-frags (294912 B);
                               // fused fallback: 12*36864 float2 stage-1 DFT
#define XS_OFF    3624192      // 12*36864 float2 shifted spectrum
#define AH_OFF    7163136      // 36864 float2 ifftshifted A_tot
#define XF_OFF    7458048      // 64*36864 float xf (split). r7: also t1a/t1b
                               // partial stage-1 tiles (2x 3538944 B) before
                               // k_ifftm overwrites with xf.
#define T1B_HALF  3538944      // byte offset of t1b within XF region
#define E2B_OFF   15846656     // XF_OFF+8MB: 294912 B stage-2 twiddle B-frags
#define WS_FUSED  7458048
#define WS_SPLIT  16895232

// d_out used as scratch before k_conv overwrites it (out = 37.7 MB):
#define PH_BYTES  14155776     // Ph prefix table: 96 levels * 96 w * 192 y * float2
#define E2C_OFF   14155776     // 147456 B: K=192 cos/sin bf16 hi/lo B-frags
// out tensor = [4,64,192,192] f32 = 37748736 B = 9437184 elems. Gate on the
// element count so the check passes whether out_size is bytes OR elements.
#define OUT_MIN_ELEMS 9437184

typedef __attribute__((ext_vector_type(8))) short short8;
typedef __attribute__((ext_vector_type(4))) float floatx4;

__device__ __forceinline__ void bf16split(float v, unsigned short& hi, unsigned short& lo) {
    unsigned ub = __builtin_bit_cast(unsigned, v);
    hi = (unsigned short)(ub >> 16);
    float vh = __builtin_bit_cast(float, ub & 0xFFFF0000u);
    lo = (unsigned short)(__builtin_bit_cast(unsigned, v - vh) >> 16);
}

// ---------------- K0: precompute twiddles, params, frag tables, intervals ---
__global__ void k_pre(const float* freq, const float* theta, const float* sigma,
                      const float* f0, const float* theta0, const float* fbs,
                      const float* w1, const float* b1v, const float* w2,
                      char* ws, char* outw, int split) {
    float2* tw   = (float2*)(ws + TW_OFF);
    float4* pcA  = (float4*)(ws + PCA_OFF);
    float2* pcB  = (float2*)(ws + PCB_OFF);
    float4* w1f4 = (float4*)(ws + W1F4_OFF);
    unsigned short* w2b = (unsigned short*)(ws + W2B_OFF);
    int* idx = (int*)(ws + IDX_OFF);
    int gtid = blockIdx.x * blockDim.x + threadIdx.x;
    int gsz  = gridDim.x * blockDim.x;
    for (int n = gtid; n < 192; n += gsz) {
        float th = PI2 * (float)n / 192.0f;
        tw[n] = make_float2(cosf(th), sinf(th));
    }
    for (int t = gtid; t < 576; t += gsz) {
        int s = t / 192, rem = t % 192, o = rem / 3, i = rem % 3;
        float fr = freq[t], th = theta[t], sg = sigma[t], f0v = f0[t], th0 = theta0[t];
        float lg  = logf(sg / f0v);
        float a1  = -1.0f / (2.0f * lg * lg);
        float lf0 = logf(f0v);
        float a2  = -1.0f / (2.0f * th0 * th0);
        float lsc = -logf(PI2 * sg * sg);          // log(1/(2pi sg^2))
        int pidx = (s*3 + i)*64 + o;
        pcA[pidx] = make_float4(a1, lf0, a2, th);
        pcB[pidx] = make_float2(fr, lsc);
    }
    for (int t = gtid; t < 64; t += gsz)
        w1f4[t] = make_float4(w1[t*3+0], w1[t*3+1], w1[t*3+2], b1v[t]);
    // W2 B-fragments, t-MAJOR layout (r6): entry u = ((t*2+kc)*2+hsel)*512 +
    // l*8 + j.
    for (int u = gtid; u < 24576; u += gsz) {
        int j = u & 7;
        int l = (u >> 3) & 63;
        int hsel = (u >> 9) & 1;
        int rest = u >> 10;              // t*2 + kc
        int kc = rest & 1;
        int t = rest >> 1;
        int k = kc*32 + (l>>4)*8 + j;
        int c = t*16 + (l & 15);
        float wv = w2[c*64 + k];
        unsigned short hi, lo;
        bf16split(wv, hi, lo);
        w2b[u] = hsel ? lo : hi;
    }
    for (int t = gtid; t < 192; t += gsz) {
        int lo = (int)floorf((fbs[t*2+0] + 1.0f) * 0.5f * 192.0f) - 96;
        int hi = (int)floorf((fbs[t*2+1] + 1.0f) * 0.5f * 192.0f) - 96;
        lo = max(0, min(96, lo));
        hi = max(0, min(96, hi));
        if (hi < lo) hi = lo;
        idx[t*2+0] = lo; idx[t*2+1] = hi;
    }
    if (split) {
        // Stage-2 DFT twiddle B-frags: B_re[k][n], K=384, N=192.
        // offset = ((t*12+kc)*2+half)*512 + lane*8 + j  (shorts)
        unsigned short* e2b = (unsigned short*)(ws + E2B_OFF);
        for (int u = gtid; u < 147456; u += gsz) {
            int j = u & 7;
            int l = (u >> 3) & 63;
            int half = (u >> 9) & 1;
            int rest = u >> 10;              // t*12 + kc
            int kc = rest % 12, t = rest / 12;
            int k = kc*32 + ((l >> 4) << 3) + j;
            int w = k >> 1, comp = k & 1;
            int n = t*16 + (l & 15);
            int ang = (w * n) % 192;
            float th = PI2 * (float)ang / 192.0f;
            float v = comp ? sinf(th) : cosf(th);
            unsigned short hi, lo;
            bf16split(v, hi, lo);
            e2b[u] = half ? lo : hi;
        }
        // Stage-1 DFT twiddle A-frags (k_dft1m): A[y][h],
        // comp 0 = cos(2pi h y/192), comp 1 = -sin (e^{-i}).
        // Layout: ((yt*2+comp)*6+kc)*2+half)*512 + lane*8 + j; row y =
        // yt*16+(l&15), k h = kc*32+((l>>4)<<3)+j. Lives at T1_OFF.
        unsigned short* e1 = (unsigned short*)(ws + T1_OFF);
        for (int u = gtid; u < 147456; u += gsz) {
            int j = u & 7;
            int l = (u >> 3) & 63;
            int half = (u >> 9) & 1;
            int rest = u >> 10;              // yt*12 + comp*6 + kc
            int kc = rest % 6;
            int comp = (rest / 6) & 1;
            int yt = rest / 12;
            int y = yt*16 + (l & 15);
            int h = kc*32 + ((l >> 4) << 3) + j;
            int ang = (h * y) % 192;
            float th = PI2 * (float)ang / 192.0f;
            float v = comp ? -sinf(th) : cosf(th);
            unsigned short hi, lo;
            bf16split(v, hi, lo);
            e1[u] = half ? lo : hi;
        }
        // IFFT B-frags (K=192, kc 0..5 only) — in d_out.
        // Layout: ((t*6+kc)*2+half)*512 + lane*8 + j  (shorts)
        unsigned short* e2c = (unsigned short*)(outw + E2C_OFF);
        for (int u = gtid; u < 73728; u += gsz) {
            int j = u & 7;
            int l = (u >> 3) & 63;
            int half = (u >> 9) & 1;
            int rest = u >> 10;              // t*6 + kc
            int kc = rest % 6, t = rest / 6;
            int k = kc*32 + ((l >> 4) << 3) + j;
            int w = k >> 1, comp = k & 1;
            int n = t*16 + (l & 15);
            int ang = (w * n) % 192;
            float th = PI2 * (float)ang / 192.0f;
            float v = comp ? sinf(th) : cosf(th);
            unsigned short hi, lo;
            bf16split(v, hi, lo);
            e2c[u] = half ? lo : hi;
        }
    }
}

// ---------------- K1a (split): MFMA stage-1 DFT, h-half partials ------------
// r7: the fused k_dftm ran 144 blocks on 256 CUs (1 wave/SIMD, 112 CUs idle)
// with scalar x-loads whose L2 latency had no TLP to hide under. Split:
// block = (bi, yt, z in {0,1}) -> 288 blocks, K=96 per block (kc = z*3+kq).
// Partial T1 tiles land in the XF region (t1a/t1b), added by k_dft2m --
// the same partial-sum structure r2/r4 ran. Stage-1 math/tables unchanged.
__global__ __launch_bounds__(256) void k_dft1m(const float* x, char* ws) {
    const unsigned short* e1 = (const unsigned short*)(ws + T1_OFF);
    int tid = threadIdx.x;
    int b = blockIdx.x;
    int z  = b & 1;
    int yt = (b >> 1) % 12;
    int bi = b / 24;
    int y0 = yt * 16;
    int wave = tid >> 6, lane = tid & 63;
    int ml = lane & 15, qd = lane >> 4;
    const float* xp = x + bi * NPIX;
    union AB { short8 v; unsigned short u[8]; };
    floatx4 s1re[3], s1im[3];
#pragma unroll
    for (int tt = 0; tt < 3; tt++) {
        s1re[tt] = (floatx4){0.f,0.f,0.f,0.f};
        s1im[tt] = (floatx4){0.f,0.f,0.f,0.f};
    }
#pragma unroll 1
    for (int kq = 0; kq < 3; kq++) {
        int kc = z*3 + kq;                 // h block kc*32..+32
        const unsigned short* ac = e1 + (((((yt*2 + 0)*6 + kc)*2) << 9) + (lane << 3));
        const unsigned short* as = e1 + (((((yt*2 + 1)*6 + kc)*2) << 9) + (lane << 3));
        short8 ach = *(const short8*)ac;
        short8 acl = *(const short8*)(ac + 512);
        short8 ash = *(const short8*)as;
        short8 asl = *(const short8*)(as + 512);
#pragma unroll
        for (int tt = 0; tt < 3; tt++) {
            int nt = wave*3 + tt;
            AB bh8, bl8;
#pragma unroll
            for (int j = 0; j < 8; j++) {
                int h = kc*32 + qd*8 + j;
                float xv = xp[h*192 + nt*16 + ml];
                bf16split(xv, bh8.u[j], bl8.u[j]);
            }
            floatx4 r = s1re[tt];
            r = __builtin_amdgcn_mfma_f32_16x16x32_bf16(ach, bh8.v, r, 0, 0, 0);
            r = __builtin_amdgcn_mfma_f32_16x16x32_bf16(acl, bh8.v, r, 0, 0, 0);
            r = __builtin_amdgcn_mfma_f32_16x16x32_bf16(ach, bl8.v, r, 0, 0, 0);
            s1re[tt] = r;
            floatx4 q = s1im[tt];
            q = __builtin_amdgcn_mfma_f32_16x16x32_bf16(ash, bh8.v, q, 0, 0, 0);
            q = __builtin_amdgcn_mfma_f32_16x16x32_bf16(asl, bh8.v, q, 0, 0, 0);
            q = __builtin_amdgcn_mfma_f32_16x16x32_bf16(ash, bl8.v, q, 0, 0, 0);
            s1im[tt] = q;
        }
    }
    float2* op = (float2*)(ws + XF_OFF + (size_t)z * T1B_HALF) + bi * NPIX;
#pragma unroll
    for (int tt = 0; tt < 3; tt++) {
        int w = (wave*3 + tt)*16 + ml;
#pragma unroll
        for (int r = 0; r < 4; r++)
            op[(y0 + qd*4 + r)*192 + w] = make_float2(s1re[tt][r], s1im[tt][r]);
    }
}

// ---------------- K1b (split): stage-2 DFT as MFMA matmul + fftshift --------
// r2-proven body: t1a+t1b add -> LDS Ar -> K=384 re/im MFMA (e2b) -> scatter.
__global__ __launch_bounds__(256) void k_dft2m(char* ws) {
    __shared__ __align__(16) float2 Ar[16][194];
    const float2* t1a = (const float2*)(ws + XF_OFF);
    const float2* t1b = (const float2*)(ws + XF_OFF + T1B_HALF);
    const unsigned short* e2b = (const unsigned short*)(ws + E2B_OFF);
    float2* Xs = (float2*)(ws + XS_OFF);
    int tid = threadIdx.x;
    int bi = blockIdx.x / 12;
    int y0 = (blockIdx.x % 12) * 16;
    for (int u = tid; u < 3072; u += 256) {
        int m = u / 192, w = u - m*192;
        float2 v = t1a[bi*NPIX + (y0+m)*192 + w];
        float2 v2 = t1b[bi*NPIX + (y0+m)*192 + w];
        v.x += v2.x; v.y += v2.y;
        Ar[m][w] = v;
    }
    __syncthreads();
    int wave = tid >> 6, lane = tid & 63;
    int ml = lane & 15, qd = lane >> 4;
    floatx4 accre[3], accim[3];
#pragma unroll
    for (int tt = 0; tt < 3; tt++) {
        accre[tt] = (floatx4){0.f,0.f,0.f,0.f};
        accim[tt] = (floatx4){0.f,0.f,0.f,0.f};
    }
    union AB { short8 v; unsigned short u[8]; };
#pragma unroll 1
    for (int kc = 0; kc < 12; kc++) {
        int wb = kc*16 + qd*4;
        float4 p01 = *(const float4*)&Ar[ml][wb];
        float4 p23 = *(const float4*)&Ar[ml][wb + 2];
        float av[8]  = {p01.x, p01.y, p01.z, p01.w, p23.x, p23.y, p23.z, p23.w};
        float apv[8] = {p01.y, -p01.x, p01.w, -p01.z, p23.y, -p23.x, p23.w, -p23.z};
        AB ah, al, aph, apl;
#pragma unroll
        for (int j = 0; j < 8; j++) {
            bf16split(av[j],  ah.u[j],  al.u[j]);
            bf16split(apv[j], aph.u[j], apl.u[j]);
        }
#pragma unroll
        for (int tt = 0; tt < 3; tt++) {
            int t = wave*3 + tt;
            const unsigned short* bp = e2b + (((t*12 + kc)*2) << 9) + (lane << 3);
            short8 bh = *(const short8*)bp;
            short8 bl = *(const short8*)(bp + 512);
            floatx4 r = accre[tt];
            r = __builtin_amdgcn_mfma_f32_16x16x32_bf16(ah.v,  bh, r, 0, 0, 0);
            r = __builtin_amdgcn_mfma_f32_16x16x32_bf16(al.v,  bh, r, 0, 0, 0);
            r = __builtin_amdgcn_mfma_f32_16x16x32_bf16(ah.v,  bl, r, 0, 0, 0);
            accre[tt] = r;
            floatx4 q = accim[tt];
            q = __builtin_amdgcn_mfma_f32_16x16x32_bf16(aph.v, bh, q, 0, 0, 0);
            q = __builtin_amdgcn_mfma_f32_16x16x32_bf16(apl.v, bh, q, 0, 0, 0);
            q = __builtin_amdgcn_mfma_f32_16x16x32_bf16(aph.v, bl, q, 0, 0, 0);
            accim[tt] = q;
        }
    }
    int b = bi / 3, i = bi % 3;
    int bs = (b + 2) & 3;
    int is = (i + 1) % 3;
    float2* Xp = Xs + (bs*3 + is)*NPIX;
#pragma unroll
    for (int tt = 0; tt < 3; tt++) {
        int kx = (wave*3 + tt)*16 + ml;
        int ks = kx + 96; if (ks >= 192) ks -= 192;
#pragma unroll
        for (int r = 0; r < 4; r++) {
            int y = y0 + qd*4 + r;
            int ys = y + 96; if (ys >= 192) ys -= 192;
            Xp[ys*192 + ks] = make_float2(accre[tt][r], accim[tt][r]);
        }
    }
}

// ---------------- K1 (fallback, fused path): full-h stage-1 DFT -------------
__global__ __launch_bounds__(192) void k_dft1(const float* x, char* ws) {
    __shared__ float2 twsh[192];
    const float2* tw = (const float2*)(ws + TW_OFF);
    float2* t1 = (float2*)(ws + T1_OFF);
    int tid = threadIdx.x;
    twsh[tid] = tw[tid];
    __syncthreads();
    int bi = blockIdx.x;
    int y0 = blockIdx.y * 4;
    int w  = tid;
    const float* xp = x + bi * NPIX;
    float2 acc[4];
#pragma unroll
    for (int d = 0; d < 4; d++) acc[d] = make_float2(0.f, 0.f);
    for (int h = 0; h < 192; h++) {
        float xv = xp[h*192 + w];
        int m = (h * y0) % 192;
#pragma unroll
        for (int d = 0; d < 4; d++) {
            float2 e = twsh[m];
            acc[d].x += xv * e.x;
            acc[d].y -= xv * e.y;
            m += h; if (m >= 192) m -= 192;
        }
    }
    float2* op = t1 + bi * NPIX;
#pragma unroll
    for (int d = 0; d < 4; d++) op[(y0 + d)*192 + w] = acc[d];
}

// ---------------- K2 (fallback, fused path): scalar stage-2 DFT -------------
__global__ __launch_bounds__(192) void k_dft2(char* ws) {
    __shared__ float2 twsh[192];
    __shared__ float2 row[192];
    const float2* tw = (const float2*)(ws + TW_OFF);
    const float2* t1a = (const float2*)(ws + T1_OFF);
    float2* Xs = (float2*)(ws + XS_OFF);
    int tid = threadIdx.x;
    int bi = blockIdx.x, y = blockIdx.y;
    twsh[tid] = tw[tid];
    row[tid] = t1a[bi*NPIX + y*192 + tid];
    __syncthreads();
    int kx = tid;
    float2 st = twsh[kx];
    float2 acc = make_float2(0.f, 0.f);
#pragma unroll 1
    for (int w0 = 0; w0 < 192; w0 += 32) {
        float2 e = twsh[(w0 * kx) % 192];
#pragma unroll
        for (int w = 0; w < 32; w++) {
            float2 t = row[w0 + w];
            acc.x += t.x*e.x + t.y*e.y;          // t * conj(e)
            acc.y += t.y*e.x - t.x*e.y;
            float ex = e.x*st.x - e.y*st.y;
            e.y = e.x*st.y + e.y*st.x;
            e.x = ex;
        }
    }
    int b = bi / 3, i = bi % 3;
    int bs = (b + 2) & 3;
    int is = (i + 1) % 3;
    int ys = y + 96;  if (ys >= 192) ys -= 192;
    int ks = kx + 96; if (ks >= 192) ks -= 192;
    Xs[(bs*3 + is)*NPIX + ys*192 + ks] = acc;
}

// ---------------- K3: MFMA SYRK for BN stats: M2 = H1^T H1, m1 = sum(H1) ----
__global__ __launch_bounds__(256) void k_stats(char* ws) {
    __shared__ float magL[192];                    // [s][i] at s*3+i
    __shared__ float4 w1L[64];
    __shared__ float m1L[64];
    __shared__ __align__(16) unsigned short fragH[512*8];  // z*8, z=(kc*4+cb)*64+l
    __shared__ __align__(16) unsigned short fragL[512*8];
    const float2* Xs = (const float2*)(ws + XS_OFF);
    float* M2 = (float*)(ws + M2_OFF);
    int tid = threadIdx.x;
    int wave = tid >> 6, lane = tid & 63;
    if (tid < 64) { w1L[tid] = ((const float4*)(ws + W1F4_OFF))[tid]; m1L[tid] = 0.f; }
    __syncthreads();
    int cch = wave*16 + (lane & 15);               // this thread's channel
    float4 wf = w1L[cch];
    float msum = 0.f;
    floatx4 acc[4];
#pragma unroll
    for (int nb = 0; nb < 4; nb++) acc[nb] = (floatx4){0.f, 0.f, 0.f, 0.f};
    union AB { short8 v; unsigned short u[8]; };
#pragma unroll 1
    for (int it = 0; it < 2; it++) {
        int tile = blockIdx.x * 2 + it;            // 1152*2 = 2304 tiles
        int S0 = tile * 64;
        int b = S0 / NPIX;                         // NPIX%64==0 -> const per tile
        int p0 = S0 - b*NPIX;
        if (tid < 192) {
            int i = tid >> 6, s = tid & 63;
            float2 v = Xs[(b*3 + i)*NPIX + p0 + s];
            magL[s*3 + i] = sqrtf(v.x*v.x + v.y*v.y);
        }
        __syncthreads();
#pragma unroll
        for (int kc = 0; kc < 2; kc++) {
            AB h8, l8;
#pragma unroll
            for (int j = 0; j < 8; j++) {
                int s = kc*32 + (lane>>4)*8 + j;
                float mg0 = magL[s*3], mg1 = magL[s*3+1], mg2 = magL[s*3+2];
                float hv = fmaxf(wf.w + wf.x*mg0 + wf.y*mg1 + wf.z*mg2, 0.f);
                msum += hv;
                bf16split(hv, h8.u[j], l8.u[j]);
            }
            int z = (kc*4 + wave)*64 + lane;
            *(short8*)&fragH[z*8] = h8.v;
            *(short8*)&fragL[z*8] = l8.v;
        }
        __syncthreads();
        short8 Ah0 = *(const short8*)&fragH[((0*4+wave)*64 + lane)*8];
        short8 Ah1 = *(const short8*)&fragH[((1*4+wave)*64 + lane)*8];
        short8 Al0 = *(const short8*)&fragL[((0*4+wave)*64 + lane)*8];
        short8 Al1 = *(const short8*)&fragL[((1*4+wave)*64 + lane)*8];
#pragma unroll
        for (int nb = 0; nb < 4; nb++) {
            short8 Bh0 = *(const short8*)&fragH[((0*4+nb)*64 + lane)*8];
            short8 Bh1 = *(const short8*)&fragH[((1*4+nb)*64 + lane)*8];
            short8 Bl0 = *(const short8*)&fragL[((0*4+nb)*64 + lane)*8];
            short8 Bl1 = *(const short8*)&fragL[((1*4+nb)*64 + lane)*8];
            floatx4 a = acc[nb];
            a = __builtin_amdgcn_mfma_f32_16x16x32_bf16(Ah0, Bh0, a, 0, 0, 0);
            a = __builtin_amdgcn_mfma_f32_16x16x32_bf16(Al0, Bh0, a, 0, 0, 0);
            a = __builtin_amdgcn_mfma_f32_16x16x32_bf16(Ah0, Bl0, a, 0, 0, 0);
            a = __builtin_amdgcn_mfma_f32_16x16x32_bf16(Ah1, Bh1, a, 0, 0, 0);
            a = __builtin_amdgcn_mfma_f32_16x16x32_bf16(Al1, Bh1, a, 0, 0, 0);
            a = __builtin_amdgcn_mfma_f32_16x16x32_bf16(Ah1, Bl1, a, 0, 0, 0);
            acc[nb] = a;
        }
        __syncthreads();
    }
#pragma unroll
    for (int nb = 0; nb < 4; nb++)
#pragma unroll
        for (int r = 0; r < 4; r++) {
            int row = wave*16 + (lane>>4)*4 + r;
            int col = nb*16 + (lane & 15);
            atomicAdd(&M2[row*64 + col], acc[nb][r]);
        }
    atomicAdd(&m1L[cch], msum);
    __syncthreads();
    if (tid < 64) atomicAdd(&M2[4096 + tid], m1L[tid]);
}

// ---------------- K4: BN scale/shift, one block per channel -----------------
__global__ __launch_bounds__(64) void k_bn(const float* w2, const float* bnw,
                                           const float* bnb, char* ws) {
    const float* M2 = (const float*)(ws + M2_OFF);
    const float* m1 = M2 + 4096;
    float* bnsc = (float*)(ws + BN_OFF);
    float* bnsh = bnsc + 192;
    int c = blockIdx.x;
    int jj = threadIdx.x;
    const float* row = w2 + c*64;
    float rj = row[jj];
    float inner = 0.f;
    const float* m2r = M2 + jj*64;
    for (int k = 0; k < 64; k++) inner += row[k] * m2r[k];
    float qpart = rj * inner;
    float dpart = rj * m1[jj];
#pragma unroll
    for (int sh = 32; sh >= 1; sh >>= 1) {
        qpart += __shfl_xor(qpart, sh);
        dpart += __shfl_xor(dpart, sh);
    }
    if (jj == 0) {
        const float invN = 1.0f / 147456.0f;
        float d = dpart * invN;
        float qv = qpart * invN;
        float var = qv - d*d;
        float rstd = rsqrtf(var + 1e-5f);
        float scale = bnw[c] * rstd;
        bnsc[c] = scale;
        bnsh[c] = bnb[c] - d * scale;
    }
}

// ---------------- K5: MFMA attention + gabor -> A_tot (online softmax) ------
__global__ __launch_bounds__(256) void k_attn(char* ws) {
    __shared__ __align__(16) float4 pcAL[576];
    __shared__ float2 pcBL[576];
    __shared__ float4 w1L[64];
    const float2* Xs = (const float2*)(ws + XS_OFF);
    const float* bnA = (const float*)(ws + BN_OFF);   // [0..192) scale, [192..384) shift
    const char* W2G = (const char*)(ws + W2B_OFF);
    float2* Ah = (float2*)(ws + AH_OFF);
    int tid = threadIdx.x;
    {
        const float4* pcA4 = (const float4*)(ws + PCA_OFF);
        const float2* pcB2 = (const float2*)(ws + PCB_OFF);
        for (int u = tid; u < 576; u += 256) {
            pcAL[u] = pcA4[u];
            pcBL[u] = pcB2[u];
        }
        if (tid < 64) w1L[tid] = ((const float4*)(ws + W1F4_OFF))[tid];
    }
    __syncthreads();
    int wave = tid >> 6, lane = tid & 63;
    int cl = lane & 15, q = lane >> 4;
    int g = blockIdx.x * 4 + wave;
    int pix0 = g * 4;

    union AB { short8 v; unsigned short u[8]; };
    int pb = pix0 + (cl >> 2), bb = cl & 3;
    float2 q0 = Xs[(bb*3+0)*NPIX + pb];
    float2 q1 = Xs[(bb*3+1)*NPIX + pb];
    float2 q2 = Xs[(bb*3+2)*NPIX + pb];
    float mg0 = sqrtf(q0.x*q0.x + q0.y*q0.y);
    float mg1 = sqrtf(q1.x*q1.x + q1.y*q1.y);
    float mg2 = sqrtf(q2.x*q2.x + q2.y*q2.y);
    AB ah[2], al[2];
#pragma unroll
    for (int kc = 0; kc < 2; kc++)
#pragma unroll
        for (int j = 0; j < 8; j++) {
            int k = kc*32 + q*8 + j;
            float4 wf = w1L[k];
            float hv = fmaxf(wf.w + wf.x*mg0 + wf.y*mg1 + wf.z*mg2, 0.f);
            bf16split(hv, ah[kc].u[j], al[kc].u[j]);
        }
    int pixE = pix0 + q;
    int hh = pixE / 192, ww = pixE - hh*192;
    float yy = -1.0f + (float)hh * (2.0f/191.0f);
    float xx = -1.0f + (float)ww * (2.0f/191.0f);
    float rr = sqrtf(xx*xx + yy*yy + 1e-6f);
    float lr = __logf(rr);
    float phi = atan2f(yy, xx);
    float sm0 = 0.f, sm1 = 0.f, sm2 = 0.f, sm3 = 0.f;
    float Wr[4][3];
#pragma unroll
    for (int r = 0; r < 4; r++) { Wr[r][0] = 0.f; Wr[r][1] = 0.f; Wr[r][2] = 0.f; }
#pragma unroll 2
    for (int t = 0; t < 12; t++) {
        floatx4 a = {0.f, 0.f, 0.f, 0.f};
#pragma unroll
        for (int kc = 0; kc < 2; kc++) {
            int ob = (((t*2 + kc)*2)*64 + lane)*16;      // t-major (r6)
            short8 bh = *(const short8*)(W2G + ob);
            short8 bl = *(const short8*)(W2G + ob + 1024);
            a = __builtin_amdgcn_mfma_f32_16x16x32_bf16(ah[kc].v, bh, a, 0, 0, 0);
            a = __builtin_amdgcn_mfma_f32_16x16x32_bf16(al[kc].v, bh, a, 0, 0, 0);
            a = __builtin_amdgcn_mfma_f32_16x16x32_bf16(ah[kc].v, bl, a, 0, 0, 0);
        }
        int c = t*16 + cl;
        float sc_ = bnA[c], sh_ = bnA[192 + c];
        float e0 = __expf(a[0]*sc_ + sh_);
        float e1 = __expf(a[1]*sc_ + sh_);
        float e2 = __expf(a[2]*sc_ + sh_);
        float e3 = __expf(a[3]*sc_ + sh_);
        sm0 += e0; sm1 += e1; sm2 += e2; sm3 += e3;
        int sB = c >> 6, o = c & 63;
#pragma unroll
        for (int i = 0; i < 3; i++) {
            int pidx = (sB*3 + i)*64 + o;
            float4 pa = pcAL[pidx];
            float2 pbv = pcBL[pidx];
            float dl = lr - pa.y, dp = phi - pa.w;
            float gv = __expf(pa.x*dl*dl + pa.z*dp*dp + pbv.y) * __cosf(pbv.x*rr);
            Wr[0][i] += e0*gv; Wr[1][i] += e1*gv;
            Wr[2][i] += e2*gv; Wr[3][i] += e3*gv;
        }
    }
#pragma unroll
    for (int sh = 1; sh < 16; sh <<= 1) {
        sm0 += __shfl_xor(sm0, sh); sm1 += __shfl_xor(sm1, sh);
        sm2 += __shfl_xor(sm2, sh); sm3 += __shfl_xor(sm3, sh);
    }
    float inv0 = 1.0f/sm0, inv1 = 1.0f/sm1, inv2 = 1.0f/sm2, inv3 = 1.0f/sm3;
    float are = 0.f, aim = 0.f;
#pragma unroll
    for (int i = 0; i < 3; i++) {
        float2 x0 = Xs[(0*3+i)*NPIX + pixE];
        float2 x1 = Xs[(1*3+i)*NPIX + pixE];
        float2 x2 = Xs[(2*3+i)*NPIX + pixE];
        float2 x3 = Xs[(3*3+i)*NPIX + pixE];
        float w0v = Wr[0][i]*inv0, w1v = Wr[1][i]*inv1;
        float w2v = Wr[2][i]*inv2, w3v = Wr[3][i]*inv3;
        are += w0v*x0.x + w1v*x1.x + w2v*x2.x + w3v*x3.x;
        aim += w0v*x0.y + w1v*x1.y + w2v*x2.y + w3v*x3.y;
    }
#pragma unroll
    for (int sh = 1; sh < 16; sh <<= 1) {
        are += __shfl_xor(are, sh);
        aim += __shfl_xor(aim, sh);
    }
    if (cl == 0) {
        int hs = hh + 96; if (hs >= 192) hs -= 192;
        int wsx = ww + 96; if (wsx >= 192) wsx -= 192;
        Ah[hs*192 + wsx] = make_float2(are, aim);
    }
}

// ---------------- K6a-1: h-prefix column DFT table (split path) -------------
__global__ __launch_bounds__(192) void k_phpre(char* ws, char* outw) {
    __shared__ float2 AhL[96];
    const float2* tw  = (const float2*)(ws + TW_OFF);
    const float2* Ahp = (const float2*)(ws + AH_OFF);
    float2* Ph = (float2*)outw;
    int y = threadIdx.x;                 // 0..191
    int w = blockIdx.x;                  // 0..95
    if (y < 96) AhL[y] = Ahp[y*192 + w];
    __syncthreads();
    float2 step = tw[y];
    float ex = 1.f, ey = 0.f;            // e^{+2pi i h y/192}, h=0
    float ax = 0.f, ay = 0.f;
    for (int h = 0; h < 96; h++) {
        float2 a = AhL[h];
        ax += a.x*ex - a.y*ey;
        ay += a.x*ey + a.y*ex;
        Ph[(h*96 + w)*192 + y] = make_float2(ax, ay);
        float t = ex*step.x - ey*step.y;
        ey = ex*step.y + ey*step.x;
        ex = t;
    }
}

// ---------------- K6a-2: masked IDFT as MFMA matmul (split path) ------------
__global__ __launch_bounds__(256) void k_ifftm(char* ws, char* outw) {
    __shared__ __align__(16) unsigned short AhiL[16*200];  // [yy][k], pad 192->200
    __shared__ __align__(16) unsigned short AloL[16*200];
    __shared__ int iL[3], iH[3];
    const float2* Ph = (const float2*)outw;
    const unsigned short* e2c = (const unsigned short*)(outw + E2C_OFF);
    const int* idx = (const int*)(ws + IDX_OFF);
    float* xf = (float*)(ws + XF_OFF);
    int tid = threadIdx.x;
    int o  = blockIdx.x / 12;
    int ys = blockIdx.x % 12;            // 16-row slab: rows ys*16 .. +15
    int op = (o + 32) & 63;              // ifftshift on the channel axis
    if (tid < 3) { iL[tid] = idx[(op*3 + tid)*2]; iH[tid] = idx[(op*3 + tid)*2 + 1]; }
    __syncthreads();
    // ---- gather Stot -> A' bf16 hi/lo fragments in LDS (1536 entries) ----
    for (int u = tid; u < 1536; u += 256) {
        int w = u >> 4, yy = u & 15;
        int y = ys*16 + yy;
        float sr = 0.f, si = 0.f;
#pragma unroll
        for (int i = 0; i < 3; i++) {
            int lo = iL[i], hi = iH[i];
            if (w >= lo && w < hi) {
                float2 a = Ph[((hi-1)*96 + w)*192 + y];
                sr += a.x; si += a.y;
                if (lo > 0) {
                    float2 b2 = Ph[((lo-1)*96 + w)*192 + y];
                    sr -= b2.x; si -= b2.y;
                }
            }
        }
        unsigned short rh, rl, ih, il;
        bf16split(sr, rh, rl);
        bf16split(-si, ih, il);
        *(unsigned*)&AhiL[yy*200 + 2*w] = (unsigned)rh | ((unsigned)ih << 16);
        *(unsigned*)&AloL[yy*200 + 2*w] = (unsigned)rl | ((unsigned)il << 16);
    }
    __syncthreads();
    // ---- MFMA: M=16 (1 m-tile), N=192 (12 n-tiles / 4 waves), K=192 ----
    int wave = tid >> 6, lane = tid & 63;
    int ml = lane & 15, qd = lane >> 4;
    const float s = 1.0f / 36864.0f;
#pragma unroll 1
    for (int ntl = 0; ntl < 3; ntl++) {
        int nt = wave*3 + ntl;
        floatx4 acc = (floatx4){0.f,0.f,0.f,0.f};
#pragma unroll
        for (int kc = 0; kc < 6; kc++) {
            const unsigned short* bp = e2c + ((nt*6 + kc) << 10) + (lane << 3);
            short8 bh = *(const short8*)bp;
            short8 bl = *(const short8*)(bp + 512);
            int ka = kc*32 + qd*8;
            short8 ah = *(const short8*)&AhiL[ml*200 + ka];
            short8 al = *(const short8*)&AloL[ml*200 + ka];
            acc = __builtin_amdgcn_mfma_f32_16x16x32_bf16(ah, bh, acc, 0, 0, 0);
            acc = __builtin_amdgcn_mfma_f32_16x16x32_bf16(al, bh, acc, 0, 0, 0);
            acc = __builtin_amdgcn_mfma_f32_16x16x32_bf16(ah, bl, acc, 0, 0, 0);
        }
#pragma unroll
        for (int r = 0; r < 4; r++) {
            int y = ys*16 + qd*4 + r;
            int x = nt*16 + ml;
            xf[o*NPIX + y*192 + x] = acc[r] * s;
        }
    }
}

// ---------------- K6b: 3x3 conv (sgpr weights) + mix (split path) -----------
__global__ __launch_bounds__(192) void k_conv(const float* x, const float* convw,
                                              const float* mixp, const float* xf,
                                              float* out) {
    int col = threadIdx.x;
    int y = blockIdx.x;
    int b = blockIdx.y;
    int o0 = blockIdx.z * 16;
    float xv[27];
#pragma unroll
    for (int i = 0; i < 3; i++)
#pragma unroll
        for (int dy = 0; dy < 3; dy++)
#pragma unroll
            for (int dx = 0; dx < 3; dx++) {
                int yq = y + dy - 1, xq = col + dx - 1;
                bool ok = (yq >= 0) & (yq < 192) & (xq >= 0) & (xq < 192);
                xv[(i*3 + dy)*3 + dx] = ok ? x[(b*3+i)*NPIX + yq*192 + xq] : 0.f;
            }
    float mixv = mixp[0];
    float onem = 1.0f - mixv;
    for (int o = o0; o < o0 + 16; o++) {
        float s = 0.f;
#pragma unroll
        for (int c = 0; c < 27; c++) s += xv[c] * convw[o*27 + c];
        float xfv = xf[o*NPIX + y*192 + col];
        out[((b*64 + o)*192 + y)*192 + col] = mixv*xfv + onem*s;
    }
}

// ---------------- K6 (fallback): fused IDFT + conv + mix --------------------
__global__ __launch_bounds__(192) void k_final(const float* x, const float* convw,
                                               const float* mixp, float* out, char* ws) {
    __shared__ float2 twsh[192];
    __shared__ float2 Ssh[3][96];
    __shared__ float cwsh[27];
    __shared__ int iL[3], iH[3];
    const float2* tw = (const float2*)(ws + TW_OFF);
    const int* idx = (const int*)(ws + IDX_OFF);
    const float2* Ah = (const float2*)(ws + AH_OFF);
    int tid = threadIdx.x;
    int y = blockIdx.x;
    int o = blockIdx.y;
    int op = (o + 32) & 63;
    twsh[tid] = tw[tid];
    if (tid < 27) cwsh[tid] = convw[o*27 + tid];
    if (tid < 3) { iL[tid] = idx[(op*3 + tid)*2]; iH[tid] = idx[(op*3 + tid)*2 + 1]; }
    __syncthreads();
    int l0 = iL[0], u0 = iH[0], l1 = iL[1], u1 = iH[1], l2 = iL[2], u2 = iH[2];
    int n0 = u0 - l0, n1 = u1 - l1, n2 = u2 - l2;
    int p1 = n0 + n1, T = p1 + n2;
    for (int t = tid; t < T; t += 192) {
        int i, off, lo, hi;
        if (t < n0)      { i = 0; off = t;      lo = l0; hi = u0; }
        else if (t < p1) { i = 1; off = t - n0; lo = l1; hi = u1; }
        else             { i = 2; off = t - p1; lo = l2; hi = u2; }
        int wq = lo + off;
        float sx = 0.f, sy = 0.f;
        int m = (lo * y) % 192;
        for (int hq = lo; hq < hi; hq++) {
            float2 a = Ah[hq*192 + wq];
            float2 e = twsh[m];
            sx += a.x*e.x - a.y*e.y;
            sy += a.x*e.y + a.y*e.x;
            m += y; if (m >= 192) m -= 192;
        }
        Ssh[i][off] = make_float2(sx, sy);
    }
    __syncthreads();
    int col = tid;
    float accre = 0.f;
#pragma unroll
    for (int i = 0; i < 3; i++) {
        int lo = iL[i];
        int wi = iH[i] - lo;
        int m = (lo * col) % 192;
        for (int off = 0; off < wi; off++) {
            float2 S = Ssh[i][off];
            float2 e = twsh[m];
            accre += S.x*e.x - S.y*e.y;
            m += col; if (m >= 192) m -= 192;
        }
    }
    float xfv = accre * (1.0f / 36864.0f);
    float mixv = mixp[0];
    float onem = 1.0f - mixv;
#pragma unroll
    for (int b = 0; b < 4; b++) {
        float s = 0.f;
#pragma unroll
        for (int i = 0; i < 3; i++) {
            const float* xp = x + (b*3 + i)*NPIX;
#pragma unroll
            for (int dy = -1; dy <= 1; dy++) {
                int yq = y + dy;
                if (yq < 0 || yq >= 192) continue;
                const float* rowp = xp + yq*192;
#pragma unroll
                for (int dx = -1; dx <= 1; dx++) {
                    int xq = col + dx;
                    if (xq < 0 || xq >= 192) continue;
                    s += rowp[xq] * cwsh[i*9 + (dy+1)*3 + (dx+1)];
                }
            }
        }
        out[((b*64 + o)*192 + y)*192 + col] = mixv*xfv + onem*s;
    }
}

extern "C" void kernel_launch(void* const* d_in, const int* in_sizes, int n_in,
                              void* d_out, int out_size, void* d_ws, size_t ws_size,
                              hipStream_t stream) {
    const float* x      = (const float*)d_in[0];
    const float* freq   = (const float*)d_in[1];
    const float* theta  = (const float*)d_in[2];
    const float* sigma  = (const float*)d_in[3];
    const float* f0     = (const float*)d_in[4];
    const float* theta0 = (const float*)d_in[5];
    const float* aw1    = (const float*)d_in[6];
    const float* ab1    = (const float*)d_in[7];
    const float* aw2    = (const float*)d_in[8];
    // d_in[9] = attn_b2: cancelled exactly by BN mean-subtraction, unused
    const float* bnw    = (const float*)d_in[10];
    const float* bnb    = (const float*)d_in[11];
    const float* mixp   = (const float*)d_in[12];
    const float* convw  = (const float*)d_in[13];
    const float* fbs    = (const float*)d_in[14];
    float* out = (float*)d_out;
    char* ws = (char*)d_ws;
    char* outc = (char*)d_out;
    if (ws_size < (size_t)WS_FUSED) return;
    // out is the full [4,64,192,192] f32 tensor (37.7 MB) -> >= 14.3 MB scratch
    // need under EITHER unit of out_size (bytes or elements).
    int split = (ws_size >= (size_t)WS_SPLIT) && (out_size >= OUT_MIN_ELEMS);

    hipMemsetAsync(ws + M2_OFF, 0, 16640, stream);
    k_pre  <<<192, 256, 0, stream>>>(freq, theta, sigma, f0, theta0, fbs,
                                     aw1, ab1, aw2, ws, outc, split);
    if (split) {
        k_dft1m<<<288, 256, 0, stream>>>(x, ws);
        k_dft2m<<<144, 256, 0, stream>>>(ws);
    } else {
        k_dft1 <<<dim3(12, 48), 192, 0, stream>>>(x, ws);
        k_dft2 <<<dim3(12, 192), 192, 0, stream>>>(ws);
    }
    k_stats<<<1152, 256, 0, stream>>>(ws);
    k_bn   <<<192, 64, 0, stream>>>(aw2, bnw, bnb, ws);
    k_attn <<<2304, 256, 0, stream>>>(ws);
    if (split) {
        k_phpre<<<96, 192, 0, stream>>>(ws, outc);
        k_ifftm<<<768, 256, 0, stream>>>(ws, outc);
        k_conv <<<dim3(192, 4, 4), 192, 0, stream>>>(x, convw, mixp,
                                                     (const float*)(ws + XF_OFF), out);
    } else {
        k_final<<<dim3(192, 64), 192, 0, stream>>>(x, convw, mixp, out, ws);
    }
}

// Round 8
// 241.300 us; speedup vs baseline: 1.0228x; 1.0228x over previous
//
#include <hip/hip_runtime.h>
#include <math.h>

// Problem constants
#define NPIX  36864            // 192*192
#define PI2   6.28318530717958647692f

// Workspace layout (bytes)
#define TW_OFF    0            // 192 float2 twiddles e^{+2pi i n/192}
#define PCA_OFF   1536         // 576 float4 {a1, lf0, a2, th}
#define PCB_OFF   10752        // 576 float2 {fr, lsc}
#define W1F4_OFF  15360        // 64 float4 {w1[0..2], b1}
#define W2B_OFF   16384        // MFMA B-frags bf16 hi/lo, t-major (r6): 49152 B
#define BN_OFF    65536        // 192 scale + 192 shift
#define IDX_OFF   67072        // 192*2 ints shifted intervals [o][i]{lo,hi}
#define M2_OFF    68608        // 64*64 M2 + 64 m1 floats (zeroed)
#define T1_OFF    85248        // split: E1 stage-1 twiddle A-frags (294912 B);
                               // fused fallback: 12*36864 float2 stage-1 DFT
#define XS_OFF    3624192      // 12*36864 float2 shifted spectrum
#define AH_OFF    7163136      // 36864 float2 ifftshifted A_tot
#define XF_OFF    7458048      // 64*36864 float xf (split); fallback T1 unused here
#define E2B_OFF   15846656     // XF_OFF+8MB: 294912 B stage-2 twiddle B-frags
#define WS_FUSED  7458048
#define WS_SPLIT  16895232

// d_out used as scratch before k_conv overwrites it (out = 37.7 MB):
#define PH_BYTES  14155776     // Ph prefix table: 96 levels * 96 w * 192 y * float2
#define E2C_OFF   14155776     // 147456 B: K=192 cos/sin bf16 hi/lo B-frags
// out tensor = [4,64,192,192] f32 = 37748736 B = 9437184 elems. Gate on the
// element count so the check passes whether out_size is bytes OR elements.
#define OUT_MIN_ELEMS 9437184

typedef __attribute__((ext_vector_type(8))) short short8;
typedef __attribute__((ext_vector_type(4))) float floatx4;

__device__ __forceinline__ void bf16split(float v, unsigned short& hi, unsigned short& lo) {
    unsigned ub = __builtin_bit_cast(unsigned, v);
    hi = (unsigned short)(ub >> 16);
    float vh = __builtin_bit_cast(float, ub & 0xFFFF0000u);
    lo = (unsigned short)(__builtin_bit_cast(unsigned, v - vh) >> 16);
}

// ---------------- K0: precompute twiddles, params, frag tables, intervals ---
__global__ void k_pre(const float* freq, const float* theta, const float* sigma,
                      const float* f0, const float* theta0, const float* fbs,
                      const float* w1, const float* b1v, const float* w2,
                      char* ws, char* outw, int split) {
    float2* tw   = (float2*)(ws + TW_OFF);
    float4* pcA  = (float4*)(ws + PCA_OFF);
    float2* pcB  = (float2*)(ws + PCB_OFF);
    float4* w1f4 = (float4*)(ws + W1F4_OFF);
    unsigned short* w2b = (unsigned short*)(ws + W2B_OFF);
    int* idx = (int*)(ws + IDX_OFF);
    int gtid = blockIdx.x * blockDim.x + threadIdx.x;
    int gsz  = gridDim.x * blockDim.x;
    for (int n = gtid; n < 192; n += gsz) {
        float th = PI2 * (float)n / 192.0f;
        tw[n] = make_float2(cosf(th), sinf(th));
    }
    for (int t = gtid; t < 576; t += gsz) {
        int s = t / 192, rem = t % 192, o = rem / 3, i = rem % 3;
        float fr = freq[t], th = theta[t], sg = sigma[t], f0v = f0[t], th0 = theta0[t];
        float lg  = logf(sg / f0v);
        float a1  = -1.0f / (2.0f * lg * lg);
        float lf0 = logf(f0v);
        float a2  = -1.0f / (2.0f * th0 * th0);
        float lsc = -logf(PI2 * sg * sg);          // log(1/(2pi sg^2))
        int pidx = (s*3 + i)*64 + o;
        pcA[pidx] = make_float4(a1, lf0, a2, th);
        pcB[pidx] = make_float2(fr, lsc);
    }
    for (int t = gtid; t < 64; t += gsz)
        w1f4[t] = make_float4(w1[t*3+0], w1[t*3+1], w1[t*3+2], b1v[t]);
    // W2 B-fragments, t-MAJOR layout (r6): entry u = ((t*2+kc)*2+hsel)*512 +
    // l*8 + j.
    for (int u = gtid; u < 24576; u += gsz) {
        int j = u & 7;
        int l = (u >> 3) & 63;
        int hsel = (u >> 9) & 1;
        int rest = u >> 10;              // t*2 + kc
        int kc = rest & 1;
        int t = rest >> 1;
        int k = kc*32 + (l>>4)*8 + j;
        int c = t*16 + (l & 15);
        float wv = w2[c*64 + k];
        unsigned short hi, lo;
        bf16split(wv, hi, lo);
        w2b[u] = hsel ? lo : hi;
    }
    for (int t = gtid; t < 192; t += gsz) {
        int lo = (int)floorf((fbs[t*2+0] + 1.0f) * 0.5f * 192.0f) - 96;
        int hi = (int)floorf((fbs[t*2+1] + 1.0f) * 0.5f * 192.0f) - 96;
        lo = max(0, min(96, lo));
        hi = max(0, min(96, hi));
        if (hi < lo) hi = lo;
        idx[t*2+0] = lo; idx[t*2+1] = hi;
    }
    if (split) {
        // Stage-2 DFT twiddle B-frags: B_re[k][n], K=384, N=192.
        // offset = ((t*12+kc)*2+half)*512 + lane*8 + j  (shorts)
        unsigned short* e2b = (unsigned short*)(ws + E2B_OFF);
        for (int u = gtid; u < 147456; u += gsz) {
            int j = u & 7;
            int l = (u >> 3) & 63;
            int half = (u >> 9) & 1;
            int rest = u >> 10;              // t*12 + kc
            int kc = rest % 12, t = rest / 12;
            int k = kc*32 + ((l >> 4) << 3) + j;
            int w = k >> 1, comp = k & 1;
            int n = t*16 + (l & 15);
            int ang = (w * n) % 192;
            float th = PI2 * (float)ang / 192.0f;
            float v = comp ? sinf(th) : cosf(th);
            unsigned short hi, lo;
            bf16split(v, hi, lo);
            e2b[u] = half ? lo : hi;
        }
        // Stage-1 DFT twiddle A-frags (fused k_dftm): A[y][h],
        // comp 0 = cos(2pi h y/192), comp 1 = -sin (e^{-i}).
        // Layout: ((yt*2+comp)*6+kc)*2+half)*512 + lane*8 + j; row y =
        // yt*16+(l&15), k h = kc*32+((l>>4)<<3)+j. Lives at T1_OFF.
        unsigned short* e1 = (unsigned short*)(ws + T1_OFF);
        for (int u = gtid; u < 147456; u += gsz) {
            int j = u & 7;
            int l = (u >> 3) & 63;
            int half = (u >> 9) & 1;
            int rest = u >> 10;              // yt*12 + comp*6 + kc
            int kc = rest % 6;
            int comp = (rest / 6) & 1;
            int yt = rest / 12;
            int y = yt*16 + (l & 15);
            int h = kc*32 + ((l >> 4) << 3) + j;
            int ang = (h * y) % 192;
            float th = PI2 * (float)ang / 192.0f;
            float v = comp ? -sinf(th) : cosf(th);
            unsigned short hi, lo;
            bf16split(v, hi, lo);
            e1[u] = half ? lo : hi;
        }
        // IFFT B-frags (K=192, kc 0..5 only) — in d_out.
        // Layout: ((t*6+kc)*2+half)*512 + lane*8 + j  (shorts)
        unsigned short* e2c = (unsigned short*)(outw + E2C_OFF);
        for (int u = gtid; u < 73728; u += gsz) {
            int j = u & 7;
            int l = (u >> 3) & 63;
            int half = (u >> 9) & 1;
            int rest = u >> 10;              // t*6 + kc
            int kc = rest % 6, t = rest / 6;
            int k = kc*32 + ((l >> 4) << 3) + j;
            int w = k >> 1, comp = k & 1;
            int n = t*16 + (l & 15);
            int ang = (w * n) % 192;
            float th = PI2 * (float)ang / 192.0f;
            float v = comp ? sinf(th) : cosf(th);
            unsigned short hi, lo;
            bf16split(v, hi, lo);
            e2c[u] = half ? lo : hi;
        }
    }
}

// ---------------- K1m (split): fused 2D DFT, both stages MFMA ---------------
// Block = (bi, 16-row y-tile). Stage 1: T1[y][w] = sum_h A[y][h] x[h][w],
// A = e^{-2pi i h y/192} from the exact-bf16 e1 table, B = x (hi/lo split on
// the fly), K=192 -> T1 tile straight into LDS Ar[16][194]. Stage 2 is the
// proven k_dft2m body (K=384 re/im over w, B = e2b) + fftshift scatter to Xs.
// r8: restored from r6 (best-measured 242.8); r7's 2-kernel split was neutral
// while adding a 7MB T1 round-trip + a launch gap.
__global__ __launch_bounds__(256) void k_dftm(const float* x, char* ws) {
    __shared__ __align__(16) float2 Ar[16][194];
    const unsigned short* e1  = (const unsigned short*)(ws + T1_OFF);
    const unsigned short* e2b = (const unsigned short*)(ws + E2B_OFF);
    float2* Xs = (float2*)(ws + XS_OFF);
    int tid = threadIdx.x;
    int bi = blockIdx.x / 12;
    int yt = blockIdx.x % 12;
    int y0 = yt * 16;
    int wave = tid >> 6, lane = tid & 63;
    int ml = lane & 15, qd = lane >> 4;
    const float* xp = x + bi * NPIX;
    union AB { short8 v; unsigned short u[8]; };
    // ---- stage 1 ----
    floatx4 s1re[3], s1im[3];
#pragma unroll
    for (int tt = 0; tt < 3; tt++) {
        s1re[tt] = (floatx4){0.f,0.f,0.f,0.f};
        s1im[tt] = (floatx4){0.f,0.f,0.f,0.f};
    }
#pragma unroll 1
    for (int kc = 0; kc < 6; kc++) {
        const unsigned short* ac = e1 + (((((yt*2 + 0)*6 + kc)*2) << 9) + (lane << 3));
        const unsigned short* as = e1 + (((((yt*2 + 1)*6 + kc)*2) << 9) + (lane << 3));
        short8 ach = *(const short8*)ac;
        short8 acl = *(const short8*)(ac + 512);
        short8 ash = *(const short8*)as;
        short8 asl = *(const short8*)(as + 512);
#pragma unroll
        for (int tt = 0; tt < 3; tt++) {
            int nt = wave*3 + tt;
            AB bh8, bl8;
#pragma unroll
            for (int j = 0; j < 8; j++) {
                int h = kc*32 + qd*8 + j;
                float xv = xp[h*192 + nt*16 + ml];
                bf16split(xv, bh8.u[j], bl8.u[j]);
            }
            floatx4 r = s1re[tt];
            r = __builtin_amdgcn_mfma_f32_16x16x32_bf16(ach, bh8.v, r, 0, 0, 0);
            r = __builtin_amdgcn_mfma_f32_16x16x32_bf16(acl, bh8.v, r, 0, 0, 0);
            r = __builtin_amdgcn_mfma_f32_16x16x32_bf16(ach, bl8.v, r, 0, 0, 0);
            s1re[tt] = r;
            floatx4 q = s1im[tt];
            q = __builtin_amdgcn_mfma_f32_16x16x32_bf16(ash, bh8.v, q, 0, 0, 0);
            q = __builtin_amdgcn_mfma_f32_16x16x32_bf16(asl, bh8.v, q, 0, 0, 0);
            q = __builtin_amdgcn_mfma_f32_16x16x32_bf16(ash, bl8.v, q, 0, 0, 0);
            s1im[tt] = q;
        }
    }
#pragma unroll
    for (int tt = 0; tt < 3; tt++) {
        int w = (wave*3 + tt)*16 + ml;
#pragma unroll
        for (int r = 0; r < 4; r++)
            Ar[qd*4 + r][w] = make_float2(s1re[tt][r], s1im[tt][r]);
    }
    __syncthreads();
    // ---- stage 2 (k_dft2m body) ----
    floatx4 accre[3], accim[3];
#pragma unroll
    for (int tt = 0; tt < 3; tt++) {
        accre[tt] = (floatx4){0.f,0.f,0.f,0.f};
        accim[tt] = (floatx4){0.f,0.f,0.f,0.f};
    }
#pragma unroll 1
    for (int kc = 0; kc < 12; kc++) {
        int wb = kc*16 + qd*4;
        float4 p01 = *(const float4*)&Ar[ml][wb];
        float4 p23 = *(const float4*)&Ar[ml][wb + 2];
        float av[8]  = {p01.x, p01.y, p01.z, p01.w, p23.x, p23.y, p23.z, p23.w};
        float apv[8] = {p01.y, -p01.x, p01.w, -p01.z, p23.y, -p23.x, p23.w, -p23.z};
        AB ah, al, aph, apl;
#pragma unroll
        for (int j = 0; j < 8; j++) {
            bf16split(av[j],  ah.u[j],  al.u[j]);
            bf16split(apv[j], aph.u[j], apl.u[j]);
        }
#pragma unroll
        for (int tt = 0; tt < 3; tt++) {
            int t = wave*3 + tt;
            const unsigned short* bp = e2b + (((t*12 + kc)*2) << 9) + (lane << 3);
            short8 bh = *(const short8*)bp;
            short8 bl = *(const short8*)(bp + 512);
            floatx4 r = accre[tt];
            r = __builtin_amdgcn_mfma_f32_16x16x32_bf16(ah.v,  bh, r, 0, 0, 0);
            r = __builtin_amdgcn_mfma_f32_16x16x32_bf16(al.v,  bh, r, 0, 0, 0);
            r = __builtin_amdgcn_mfma_f32_16x16x32_bf16(ah.v,  bl, r, 0, 0, 0);
            accre[tt] = r;
            floatx4 q = accim[tt];
            q = __builtin_amdgcn_mfma_f32_16x16x32_bf16(aph.v, bh, q, 0, 0, 0);
            q = __builtin_amdgcn_mfma_f32_16x16x32_bf16(apl.v, bh, q, 0, 0, 0);
            q = __builtin_amdgcn_mfma_f32_16x16x32_bf16(aph.v, bl, q, 0, 0, 0);
            accim[tt] = q;
        }
    }
    int b = bi / 3, i = bi % 3;
    int bs = (b + 2) & 3;
    int is = (i + 1) % 3;
    float2* Xp = Xs + (bs*3 + is)*NPIX;
#pragma unroll
    for (int tt = 0; tt < 3; tt++) {
        int kx = (wave*3 + tt)*16 + ml;
        int ks = kx + 96; if (ks >= 192) ks -= 192;
#pragma unroll
        for (int r = 0; r < 4; r++) {
            int y = y0 + qd*4 + r;
            int ys = y + 96; if (ys >= 192) ys -= 192;
            Xp[ys*192 + ks] = make_float2(accre[tt][r], accim[tt][r]);
        }
    }
}

// ---------------- K1 (fallback, fused path): full-h stage-1 DFT -------------
__global__ __launch_bounds__(192) void k_dft1(const float* x, char* ws) {
    __shared__ float2 twsh[192];
    const float2* tw = (const float2*)(ws + TW_OFF);
    float2* t1 = (float2*)(ws + T1_OFF);
    int tid = threadIdx.x;
    twsh[tid] = tw[tid];
    __syncthreads();
    int bi = blockIdx.x;
    int y0 = blockIdx.y * 4;
    int w  = tid;
    const float* xp = x + bi * NPIX;
    float2 acc[4];
#pragma unroll
    for (int d = 0; d < 4; d++) acc[d] = make_float2(0.f, 0.f);
    for (int h = 0; h < 192; h++) {
        float xv = xp[h*192 + w];
        int m = (h * y0) % 192;
#pragma unroll
        for (int d = 0; d < 4; d++) {
            float2 e = twsh[m];
            acc[d].x += xv * e.x;
            acc[d].y -= xv * e.y;
            m += h; if (m >= 192) m -= 192;
        }
    }
    float2* op = t1 + bi * NPIX;
#pragma unroll
    for (int d = 0; d < 4; d++) op[(y0 + d)*192 + w] = acc[d];
}

// ---------------- K2 (fallback, fused path): scalar stage-2 DFT -------------
__global__ __launch_bounds__(192) void k_dft2(char* ws) {
    __shared__ float2 twsh[192];
    __shared__ float2 row[192];
    const float2* tw = (const float2*)(ws + TW_OFF);
    const float2* t1a = (const float2*)(ws + T1_OFF);
    float2* Xs = (float2*)(ws + XS_OFF);
    int tid = threadIdx.x;
    int bi = blockIdx.x, y = blockIdx.y;
    twsh[tid] = tw[tid];
    row[tid] = t1a[bi*NPIX + y*192 + tid];
    __syncthreads();
    int kx = tid;
    float2 st = twsh[kx];
    float2 acc = make_float2(0.f, 0.f);
#pragma unroll 1
    for (int w0 = 0; w0 < 192; w0 += 32) {
        float2 e = twsh[(w0 * kx) % 192];
#pragma unroll
        for (int w = 0; w < 32; w++) {
            float2 t = row[w0 + w];
            acc.x += t.x*e.x + t.y*e.y;          // t * conj(e)
            acc.y += t.y*e.x - t.x*e.y;
            float ex = e.x*st.x - e.y*st.y;
            e.y = e.x*st.y + e.y*st.x;
            e.x = ex;
        }
    }
    int b = bi / 3, i = bi % 3;
    int bs = (b + 2) & 3;
    int is = (i + 1) % 3;
    int ys = y + 96;  if (ys >= 192) ys -= 192;
    int ks = kx + 96; if (ks >= 192) ks -= 192;
    Xs[(bs*3 + is)*NPIX + ys*192 + ks] = acc;
}

// ---------------- K3: MFMA SYRK for BN stats: M2 = H1^T H1, m1 = sum(H1) ----
__global__ __launch_bounds__(256) void k_stats(char* ws) {
    __shared__ float magL[192];                    // [s][i] at s*3+i
    __shared__ float4 w1L[64];
    __shared__ float m1L[64];
    __shared__ __align__(16) unsigned short fragH[512*8];  // z*8, z=(kc*4+cb)*64+l
    __shared__ __align__(16) unsigned short fragL[512*8];
    const float2* Xs = (const float2*)(ws + XS_OFF);
    float* M2 = (float*)(ws + M2_OFF);
    int tid = threadIdx.x;
    int wave = tid >> 6, lane = tid & 63;
    if (tid < 64) { w1L[tid] = ((const float4*)(ws + W1F4_OFF))[tid]; m1L[tid] = 0.f; }
    __syncthreads();
    int cch = wave*16 + (lane & 15);               // this thread's channel
    float4 wf = w1L[cch];
    float msum = 0.f;
    floatx4 acc[4];
#pragma unroll
    for (int nb = 0; nb < 4; nb++) acc[nb] = (floatx4){0.f, 0.f, 0.f, 0.f};
    union AB { short8 v; unsigned short u[8]; };
#pragma unroll 1
    for (int it = 0; it < 2; it++) {
        int tile = blockIdx.x * 2 + it;            // 1152*2 = 2304 tiles
        int S0 = tile * 64;
        int b = S0 / NPIX;                         // NPIX%64==0 -> const per tile
        int p0 = S0 - b*NPIX;
        if (tid < 192) {
            int i = tid >> 6, s = tid & 63;
            float2 v = Xs[(b*3 + i)*NPIX + p0 + s];
            magL[s*3 + i] = sqrtf(v.x*v.x + v.y*v.y);
        }
        __syncthreads();
#pragma unroll
        for (int kc = 0; kc < 2; kc++) {
            AB h8, l8;
#pragma unroll
            for (int j = 0; j < 8; j++) {
                int s = kc*32 + (lane>>4)*8 + j;
                float mg0 = magL[s*3], mg1 = magL[s*3+1], mg2 = magL[s*3+2];
                float hv = fmaxf(wf.w + wf.x*mg0 + wf.y*mg1 + wf.z*mg2, 0.f);
                msum += hv;
                bf16split(hv, h8.u[j], l8.u[j]);
            }
            int z = (kc*4 + wave)*64 + lane;
            *(short8*)&fragH[z*8] = h8.v;
            *(short8*)&fragL[z*8] = l8.v;
        }
        __syncthreads();
        short8 Ah0 = *(const short8*)&fragH[((0*4+wave)*64 + lane)*8];
        short8 Ah1 = *(const short8*)&fragH[((1*4+wave)*64 + lane)*8];
        short8 Al0 = *(const short8*)&fragL[((0*4+wave)*64 + lane)*8];
        short8 Al1 = *(const short8*)&fragL[((1*4+wave)*64 + lane)*8];
#pragma unroll
        for (int nb = 0; nb < 4; nb++) {
            short8 Bh0 = *(const short8*)&fragH[((0*4+nb)*64 + lane)*8];
            short8 Bh1 = *(const short8*)&fragH[((1*4+nb)*64 + lane)*8];
            short8 Bl0 = *(const short8*)&fragL[((0*4+nb)*64 + lane)*8];
            short8 Bl1 = *(const short8*)&fragL[((1*4+nb)*64 + lane)*8];
            floatx4 a = acc[nb];
            a = __builtin_amdgcn_mfma_f32_16x16x32_bf16(Ah0, Bh0, a, 0, 0, 0);
            a = __builtin_amdgcn_mfma_f32_16x16x32_bf16(Al0, Bh0, a, 0, 0, 0);
            a = __builtin_amdgcn_mfma_f32_16x16x32_bf16(Ah0, Bl0, a, 0, 0, 0);
            a = __builtin_amdgcn_mfma_f32_16x16x32_bf16(Ah1, Bh1, a, 0, 0, 0);
            a = __builtin_amdgcn_mfma_f32_16x16x32_bf16(Al1, Bh1, a, 0, 0, 0);
            a = __builtin_amdgcn_mfma_f32_16x16x32_bf16(Ah1, Bl1, a, 0, 0, 0);
            acc[nb] = a;
        }
        __syncthreads();
    }
#pragma unroll
    for (int nb = 0; nb < 4; nb++)
#pragma unroll
        for (int r = 0; r < 4; r++) {
            int row = wave*16 + (lane>>4)*4 + r;
            int col = nb*16 + (lane & 15);
            atomicAdd(&M2[row*64 + col], acc[nb][r]);
        }
    atomicAdd(&m1L[cch], msum);
    __syncthreads();
    if (tid < 64) atomicAdd(&M2[4096 + tid], m1L[tid]);
}

// ---------------- K4: BN scale/shift, one block per channel -----------------
__global__ __launch_bounds__(64) void k_bn(const float* w2, const float* bnw,
                                           const float* bnb, char* ws) {
    const float* M2 = (const float*)(ws + M2_OFF);
    const float* m1 = M2 + 4096;
    float* bnsc = (float*)(ws + BN_OFF);
    float* bnsh = bnsc + 192;
    int c = blockIdx.x;
    int jj = threadIdx.x;
    const float* row = w2 + c*64;
    float rj = row[jj];
    float inner = 0.f;
    const float* m2r = M2 + jj*64;
    for (int k = 0; k < 64; k++) inner += row[k] * m2r[k];
    float qpart = rj * inner;
    float dpart = rj * m1[jj];
#pragma unroll
    for (int sh = 32; sh >= 1; sh >>= 1) {
        qpart += __shfl_xor(qpart, sh);
        dpart += __shfl_xor(dpart, sh);
    }
    if (jj == 0) {
        const float invN = 1.0f / 147456.0f;
        float d = dpart * invN;
        float qv = qpart * invN;
        float var = qv - d*d;
        float rstd = rsqrtf(var + 1e-5f);
        float scale = bnw[c] * rstd;
        bnsc[c] = scale;
        bnsh[c] = bnb[c] - d * scale;
    }
}

// ---------------- K5: MFMA attention + gabor -> A_tot (online softmax) ------
__global__ __launch_bounds__(256) void k_attn(char* ws) {
    __shared__ __align__(16) float4 pcAL[576];
    __shared__ float2 pcBL[576];
    __shared__ float4 w1L[64];
    const float2* Xs = (const float2*)(ws + XS_OFF);
    const float* bnA = (const float*)(ws + BN_OFF);   // [0..192) scale, [192..384) shift
    const char* W2G = (const char*)(ws + W2B_OFF);
    float2* Ah = (float2*)(ws + AH_OFF);
    int tid = threadIdx.x;
    {
        const float4* pcA4 = (const float4*)(ws + PCA_OFF);
        const float2* pcB2 = (const float2*)(ws + PCB_OFF);
        for (int u = tid; u < 576; u += 256) {
            pcAL[u] = pcA4[u];
            pcBL[u] = pcB2[u];
        }
        if (tid < 64) w1L[tid] = ((const float4*)(ws + W1F4_OFF))[tid];
    }
    __syncthreads();
    int wave = tid >> 6, lane = tid & 63;
    int cl = lane & 15, q = lane >> 4;
    int g = blockIdx.x * 4 + wave;
    int pix0 = g * 4;

    union AB { short8 v; unsigned short u[8]; };
    int pb = pix0 + (cl >> 2), bb = cl & 3;
    float2 q0 = Xs[(bb*3+0)*NPIX + pb];
    float2 q1 = Xs[(bb*3+1)*NPIX + pb];
    float2 q2 = Xs[(bb*3+2)*NPIX + pb];
    float mg0 = sqrtf(q0.x*q0.x + q0.y*q0.y);
    float mg1 = sqrtf(q1.x*q1.x + q1.y*q1.y);
    float mg2 = sqrtf(q2.x*q2.x + q2.y*q2.y);
    AB ah[2], al[2];
#pragma unroll
    for (int kc = 0; kc < 2; kc++)
#pragma unroll
        for (int j = 0; j < 8; j++) {
            int k = kc*32 + q*8 + j;
            float4 wf = w1L[k];
            float hv = fmaxf(wf.w + wf.x*mg0 + wf.y*mg1 + wf.z*mg2, 0.f);
            bf16split(hv, ah[kc].u[j], al[kc].u[j]);
        }
    int pixE = pix0 + q;
    int hh = pixE / 192, ww = pixE - hh*192;
    float yy = -1.0f + (float)hh * (2.0f/191.0f);
    float xx = -1.0f + (float)ww * (2.0f/191.0f);
    float rr = sqrtf(xx*xx + yy*yy + 1e-6f);
    float lr = __logf(rr);
    float phi = atan2f(yy, xx);
    float sm0 = 0.f, sm1 = 0.f, sm2 = 0.f, sm3 = 0.f;
    float Wr[4][3];
#pragma unroll
    for (int r = 0; r < 4; r++) { Wr[r][0] = 0.f; Wr[r][1] = 0.f; Wr[r][2] = 0.f; }
#pragma unroll 2
    for (int t = 0; t < 12; t++) {
        floatx4 a = {0.f, 0.f, 0.f, 0.f};
#pragma unroll
        for (int kc = 0; kc < 2; kc++) {
            int ob = (((t*2 + kc)*2)*64 + lane)*16;      // t-major (r6)
            short8 bh = *(const short8*)(W2G + ob);
            short8 bl = *(const short8*)(W2G + ob + 1024);
            a = __builtin_amdgcn_mfma_f32_16x16x32_bf16(ah[kc].v, bh, a, 0, 0, 0);
            a = __builtin_amdgcn_mfma_f32_16x16x32_bf16(al[kc].v, bh, a, 0, 0, 0);
            a = __builtin_amdgcn_mfma_f32_16x16x32_bf16(ah[kc].v, bl, a, 0, 0, 0);
        }
        int c = t*16 + cl;
        float sc_ = bnA[c], sh_ = bnA[192 + c];
        float e0 = __expf(a[0]*sc_ + sh_);
        float e1 = __expf(a[1]*sc_ + sh_);
        float e2 = __expf(a[2]*sc_ + sh_);
        float e3 = __expf(a[3]*sc_ + sh_);
        sm0 += e0; sm1 += e1; sm2 += e2; sm3 += e3;
        int sB = c >> 6, o = c & 63;
#pragma unroll
        for (int i = 0; i < 3; i++) {
            int pidx = (sB*3 + i)*64 + o;
            float4 pa = pcAL[pidx];
            float2 pbv = pcBL[pidx];
            float dl = lr - pa.y, dp = phi - pa.w;
            float gv = __expf(pa.x*dl*dl + pa.z*dp*dp + pbv.y) * __cosf(pbv.x*rr);
            Wr[0][i] += e0*gv; Wr[1][i] += e1*gv;
            Wr[2][i] += e2*gv; Wr[3][i] += e3*gv;
        }
    }
#pragma unroll
    for (int sh = 1; sh < 16; sh <<= 1) {
        sm0 += __shfl_xor(sm0, sh); sm1 += __shfl_xor(sm1, sh);
        sm2 += __shfl_xor(sm2, sh); sm3 += __shfl_xor(sm3, sh);
    }
    float inv0 = 1.0f/sm0, inv1 = 1.0f/sm1, inv2 = 1.0f/sm2, inv3 = 1.0f/sm3;
    float are = 0.f, aim = 0.f;
#pragma unroll
    for (int i = 0; i < 3; i++) {
        float2 x0 = Xs[(0*3+i)*NPIX + pixE];
        float2 x1 = Xs[(1*3+i)*NPIX + pixE];
        float2 x2 = Xs[(2*3+i)*NPIX + pixE];
        float2 x3 = Xs[(3*3+i)*NPIX + pixE];
        float w0v = Wr[0][i]*inv0, w1v = Wr[1][i]*inv1;
        float w2v = Wr[2][i]*inv2, w3v = Wr[3][i]*inv3;
        are += w0v*x0.x + w1v*x1.x + w2v*x2.x + w3v*x3.x;
        aim += w0v*x0.y + w1v*x1.y + w2v*x2.y + w3v*x3.y;
    }
#pragma unroll
    for (int sh = 1; sh < 16; sh <<= 1) {
        are += __shfl_xor(are, sh);
        aim += __shfl_xor(aim, sh);
    }
    if (cl == 0) {
        int hs = hh + 96; if (hs >= 192) hs -= 192;
        int wsx = ww + 96; if (wsx >= 192) wsx -= 192;
        Ah[hs*192 + wsx] = make_float2(are, aim);
    }
}

// ---------------- K6a-1: h-prefix column DFT table (split path) -------------
// Ph[m-1][w][y] = sum_{h<m} Ah[h][w] e^{+2pi i h y/192}, m=1..96, w<96, y<192.
// r8: grid (96 w, 3 y-thirds) x 64 threads = 288 blocks (was 96x192 -> only
// 96 CUs busy) WITH the r4 LDS staging of the Ah column (alias-serialization
// fix). Same per-thread math as r4.
__global__ __launch_bounds__(64) void k_phpre(char* ws, char* outw) {
    __shared__ float2 AhL[96];
    const float2* tw  = (const float2*)(ws + TW_OFF);
    const float2* Ahp = (const float2*)(ws + AH_OFF);
    float2* Ph = (float2*)outw;
    int tid = threadIdx.x;
    int y = blockIdx.y * 64 + tid;       // 0..191
    int w = blockIdx.x;                  // 0..95
    for (int u = tid; u < 96; u += 64) AhL[u] = Ahp[u*192 + w];
    __syncthreads();
    float2 step = tw[y];
    float ex = 1.f, ey = 0.f;            // e^{+2pi i h y/192}, h=0
    float ax = 0.f, ay = 0.f;
    for (int h = 0; h < 96; h++) {
        float2 a = AhL[h];
        ax += a.x*ex - a.y*ey;
        ay += a.x*ey + a.y*ex;
        Ph[(h*96 + w)*192 + y] = make_float2(ax, ay);
        float t = ex*step.x - ey*step.y;
        ey = ex*step.y + ey*step.x;
        ex = t;
    }
}

// ---------------- K6a-2: masked IDFT as MFMA matmul (split path) ------------
__global__ __launch_bounds__(256) void k_ifftm(char* ws, char* outw) {
    __shared__ __align__(16) unsigned short AhiL[16*200];  // [yy][k], pad 192->200
    __shared__ __align__(16) unsigned short AloL[16*200];
    __shared__ int iL[3], iH[3];
    const float2* Ph = (const float2*)outw;
    const unsigned short* e2c = (const unsigned short*)(outw + E2C_OFF);
    const int* idx = (const int*)(ws + IDX_OFF);
    float* xf = (float*)(ws + XF_OFF);
    int tid = threadIdx.x;
    int o  = blockIdx.x / 12;
    int ys = blockIdx.x % 12;            // 16-row slab: rows ys*16 .. +15
    int op = (o + 32) & 63;              // ifftshift on the channel axis
    if (tid < 3) { iL[tid] = idx[(op*3 + tid)*2]; iH[tid] = idx[(op*3 + tid)*2 + 1]; }
    __syncthreads();
    // ---- gather Stot -> A' bf16 hi/lo fragments in LDS (1536 entries) ----
    for (int u = tid; u < 1536; u += 256) {
        int w = u >> 4, yy = u & 15;
        int y = ys*16 + yy;
        float sr = 0.f, si = 0.f;
#pragma unroll
        for (int i = 0; i < 3; i++) {
            int lo = iL[i], hi = iH[i];
            if (w >= lo && w < hi) {
                float2 a = Ph[((hi-1)*96 + w)*192 + y];
                sr += a.x; si += a.y;
                if (lo > 0) {
                    float2 b2 = Ph[((lo-1)*96 + w)*192 + y];
                    sr -= b2.x; si -= b2.y;
                }
            }
        }
        unsigned short rh, rl, ih, il;
        bf16split(sr, rh, rl);
        bf16split(-si, ih, il);
        *(unsigned*)&AhiL[yy*200 + 2*w] = (unsigned)rh | ((unsigned)ih << 16);
        *(unsigned*)&AloL[yy*200 + 2*w] = (unsigned)rl | ((unsigned)il << 16);
    }
    __syncthreads();
    // ---- MFMA: M=16 (1 m-tile), N=192 (12 n-tiles / 4 waves), K=192 ----
    int wave = tid >> 6, lane = tid & 63;
    int ml = lane & 15, qd = lane >> 4;
    const float s = 1.0f / 36864.0f;
#pragma unroll 1
    for (int ntl = 0; ntl < 3; ntl++) {
        int nt = wave*3 + ntl;
        floatx4 acc = (floatx4){0.f,0.f,0.f,0.f};
#pragma unroll
        for (int kc = 0; kc < 6; kc++) {
            const unsigned short* bp = e2c + ((nt*6 + kc) << 10) + (lane << 3);
            short8 bh = *(const short8*)bp;
            short8 bl = *(const short8*)(bp + 512);
            int ka = kc*32 + qd*8;
            short8 ah = *(const short8*)&AhiL[ml*200 + ka];
            short8 al = *(const short8*)&AloL[ml*200 + ka];
            acc = __builtin_amdgcn_mfma_f32_16x16x32_bf16(ah, bh, acc, 0, 0, 0);
            acc = __builtin_amdgcn_mfma_f32_16x16x32_bf16(al, bh, acc, 0, 0, 0);
            acc = __builtin_amdgcn_mfma_f32_16x16x32_bf16(ah, bl, acc, 0, 0, 0);
        }
#pragma unroll
        for (int r = 0; r < 4; r++) {
            int y = ys*16 + qd*4 + r;
            int x = nt*16 + ml;
            xf[o*NPIX + y*192 + x] = acc[r] * s;
        }
    }
}

// ---------------- K6b: 3x3 conv (sgpr weights) + mix (split path) -----------
__global__ __launch_bounds__(192) void k_conv(const float* x, const float* convw,
                                              const float* mixp, const float* xf,
                                              float* out) {
    int col = threadIdx.x;
    int y = blockIdx.x;
    int b = blockIdx.y;
    int o0 = blockIdx.z * 16;
    float xv[27];
#pragma unroll
    for (int i = 0; i < 3; i++)
#pragma unroll
        for (int dy = 0; dy < 3; dy++)
#pragma unroll
            for (int dx = 0; dx < 3; dx++) {
                int yq = y + dy - 1, xq = col + dx - 1;
                bool ok = (yq >= 0) & (yq < 192) & (xq >= 0) & (xq < 192);
                xv[(i*3 + dy)*3 + dx] = ok ? x[(b*3+i)*NPIX + yq*192 + xq] : 0.f;
            }
    float mixv = mixp[0];
    float onem = 1.0f - mixv;
    for (int o = o0; o < o0 + 16; o++) {
        float s = 0.f;
#pragma unroll
        for (int c = 0; c < 27; c++) s += xv[c] * convw[o*27 + c];
        float xfv = xf[o*NPIX + y*192 + col];
        out[((b*64 + o)*192 + y)*192 + col] = mixv*xfv + onem*s;
    }
}

// ---------------- K6 (fallback): fused IDFT + conv + mix --------------------
__global__ __launch_bounds__(192) void k_final(const float* x, const float* convw,
                                               const float* mixp, float* out, char* ws) {
    __shared__ float2 twsh[192];
    __shared__ float2 Ssh[3][96];
    __shared__ float cwsh[27];
    __shared__ int iL[3], iH[3];
    const float2* tw = (const float2*)(ws + TW_OFF);
    const int* idx = (const int*)(ws + IDX_OFF);
    const float2* Ah = (const float2*)(ws + AH_OFF);
    int tid = threadIdx.x;
    int y = blockIdx.x;
    int o = blockIdx.y;
    int op = (o + 32) & 63;
    twsh[tid] = tw[tid];
    if (tid < 27) cwsh[tid] = convw[o*27 + tid];
    if (tid < 3) { iL[tid] = idx[(op*3 + tid)*2]; iH[tid] = idx[(op*3 + tid)*2 + 1]; }
    __syncthreads();
    int l0 = iL[0], u0 = iH[0], l1 = iL[1], u1 = iH[1], l2 = iL[2], u2 = iH[2];
    int n0 = u0 - l0, n1 = u1 - l1, n2 = u2 - l2;
    int p1 = n0 + n1, T = p1 + n2;
    for (int t = tid; t < T; t += 192) {
        int i, off, lo, hi;
        if (t < n0)      { i = 0; off = t;      lo = l0; hi = u0; }
        else if (t < p1) { i = 1; off = t - n0; lo = l1; hi = u1; }
        else             { i = 2; off = t - p1; lo = l2; hi = u2; }
        int wq = lo + off;
        float sx = 0.f, sy = 0.f;
        int m = (lo * y) % 192;
        for (int hq = lo; hq < hi; hq++) {
            float2 a = Ah[hq*192 + wq];
            float2 e = twsh[m];
            sx += a.x*e.x - a.y*e.y;
            sy += a.x*e.y + a.y*e.x;
            m += y; if (m >= 192) m -= 192;
        }
        Ssh[i][off] = make_float2(sx, sy);
    }
    __syncthreads();
    int col = tid;
    float accre = 0.f;
#pragma unroll
    for (int i = 0; i < 3; i++) {
        int lo = iL[i];
        int wi = iH[i] - lo;
        int m = (lo * col) % 192;
        for (int off = 0; off < wi; off++) {
            float2 S = Ssh[i][off];
            float2 e = twsh[m];
            accre += S.x*e.x - S.y*e.y;
            m += col; if (m >= 192) m -= 192;
        }
    }
    float xfv = accre * (1.0f / 36864.0f);
    float mixv = mixp[0];
    float onem = 1.0f - mixv;
#pragma unroll
    for (int b = 0; b < 4; b++) {
        float s = 0.f;
#pragma unroll
        for (int i = 0; i < 3; i++) {
            const float* xp = x + (b*3 + i)*NPIX;
#pragma unroll
            for (int dy = -1; dy <= 1; dy++) {
                int yq = y + dy;
                if (yq < 0 || yq >= 192) continue;
                const float* rowp = xp + yq*192;
#pragma unroll
                for (int dx = -1; dx <= 1; dx++) {
                    int xq = col + dx;
                    if (xq < 0 || xq >= 192) continue;
                    s += rowp[xq] * cwsh[i*9 + (dy+1)*3 + (dx+1)];
                }
            }
        }
        out[((b*64 + o)*192 + y)*192 + col] = mixv*xfv + onem*s;
    }
}

extern "C" void kernel_launch(void* const* d_in, const int* in_sizes, int n_in,
                              void* d_out, int out_size, void* d_ws, size_t ws_size,
                              hipStream_t stream) {
    const float* x      = (const float*)d_in[0];
    const float* freq   = (const float*)d_in[1];
    const float* theta  = (const float*)d_in[2];
    const float* sigma  = (const float*)d_in[3];
    const float* f0     = (const float*)d_in[4];
    const float* theta0 = (const float*)d_in[5];
    const float* aw1    = (const float*)d_in[6];
    const float* ab1    = (const float*)d_in[7];
    const float* aw2    = (const float*)d_in[8];
    // d_in[9] = attn_b2: cancelled exactly by BN mean-subtraction, unused
    const float* bnw    = (const float*)d_in[10];
    const float* bnb    = (const float*)d_in[11];
    const float* mixp   = (const float*)d_in[12];
    const float* convw  = (const float*)d_in[13];
    const float* fbs    = (const float*)d_in[14];
    float* out = (float*)d_out;
    char* ws = (char*)d_ws;
    char* outc = (char*)d_out;
    if (ws_size < (size_t)WS_FUSED) return;
    // out is the full [4,64,192,192] f32 tensor (37.7 MB) -> >= 14.3 MB scratch
    // need under EITHER unit of out_size (bytes or elements).
    int split = (ws_size >= (size_t)WS_SPLIT) && (out_size >= OUT_MIN_ELEMS);

    hipMemsetAsync(ws + M2_OFF, 0, 16640, stream);
    k_pre  <<<192, 256, 0, stream>>>(freq, theta, sigma, f0, theta0, fbs,
                                     aw1, ab1, aw2, ws, outc, split);
    if (split) {
        k_dftm <<<144, 256, 0, stream>>>(x, ws);
    } else {
        k_dft1 <<<dim3(12, 48), 192, 0, stream>>>(x, ws);
        k_dft2 <<<dim3(12, 192), 192, 0, stream>>>(ws);
    }
    k_stats<<<1152, 256, 0, stream>>>(ws);
    k_bn   <<<192, 64, 0, stream>>>(aw2, bnw, bnb, ws);
    k_attn <<<2304, 256, 0, stream>>>(ws);
    if (split) {
        k_phpre<<<dim3(96, 3), 64, 0, stream>>>(ws, outc);
        k_ifftm<<<768, 256, 0, stream>>>(ws, outc);
        k_conv <<<dim3(192, 4, 4), 192, 0, stream>>>(x, convw, mixp,
                                                     (const float*)(ws + XF_OFF), out);
    } else {
        k_final<<<dim3(192, 64), 192, 0, stream>>>(x, convw, mixp, out, ws);
    }
}

// Round 9
// 219.677 us; speedup vs baseline: 1.1234x; 1.0984x over previous
//
#include <hip/hip_runtime.h>
#include <math.h>

// Problem constants
#define NPIX  36864            // 192*192
#define PI2   6.28318530717958647692f

// Workspace layout (bytes)
#define TW_OFF    0            // 192 float2 twiddles e^{+2pi i n/192}
#define PCA_OFF   1536         // 576 float4 {a1, lf0, a2, th}
#define PCB_OFF   10752        // 576 float2 {fr, lsc}
#define W1F4_OFF  15360        // 64 float4 {w1[0..2], b1}
#define W2B_OFF   16384        // MFMA B-frags bf16 hi/lo, t-major (r6): 49152 B
#define BN_OFF    65536        // 192 scale + 192 shift
#define IDX_OFF   67072        // 192*2 ints shifted intervals [o][i]{lo,hi}
#define M2_OFF    68608        // 64*64 M2 + 64 m1 floats (zeroed)
#define T1_OFF    85248        // split: E1 stage-1 twiddle A-frags (294912 B);
                               // fused fallback: 12*36864 float2 stage-1 DFT
#define XS_OFF    3624192      // 12*36864 float2 shifted spectrum
#define AH_OFF    7163136      // 36864 float2 ifftshifted A_tot
#define XF_OFF    7458048      // 64*36864 float xf (split); fallback T1 unused here
#define E2B_OFF   15846656     // XF_OFF+8MB: 294912 B stage-2 twiddle B-frags
#define WS_FUSED  7458048
#define WS_SPLIT  16895232

// d_out used as scratch before k_conv overwrites it (out = 37.7 MB):
#define PH_BYTES  14155776     // Ph prefix table: 96 levels * 96 w * 192 y * float2
#define E2C_OFF   14155776     // 147456 B: K=192 cos/sin bf16 hi/lo B-frags
// out tensor = [4,64,192,192] f32 = 37748736 B = 9437184 elems. Gate on the
// element count so the check passes whether out_size is bytes OR elements.
#define OUT_MIN_ELEMS 9437184

typedef __attribute__((ext_vector_type(8))) short short8;
typedef __attribute__((ext_vector_type(4))) float floatx4;

__device__ __forceinline__ void bf16split(float v, unsigned short& hi, unsigned short& lo) {
    unsigned ub = __builtin_bit_cast(unsigned, v);
    hi = (unsigned short)(ub >> 16);
    float vh = __builtin_bit_cast(float, ub & 0xFFFF0000u);
    lo = (unsigned short)(__builtin_bit_cast(unsigned, v - vh) >> 16);
}

// ---------------- K0: precompute twiddles, params, frag tables, intervals ---
__global__ void k_pre(const float* freq, const float* theta, const float* sigma,
                      const float* f0, const float* theta0, const float* fbs,
                      const float* w1, const float* b1v, const float* w2,
                      char* ws, char* outw, int split) {
    float2* tw   = (float2*)(ws + TW_OFF);
    float4* pcA  = (float4*)(ws + PCA_OFF);
    float2* pcB  = (float2*)(ws + PCB_OFF);
    float4* w1f4 = (float4*)(ws + W1F4_OFF);
    unsigned short* w2b = (unsigned short*)(ws + W2B_OFF);
    int* idx = (int*)(ws + IDX_OFF);
    int gtid = blockIdx.x * blockDim.x + threadIdx.x;
    int gsz  = gridDim.x * blockDim.x;
    for (int n = gtid; n < 192; n += gsz) {
        float th = PI2 * (float)n / 192.0f;
        tw[n] = make_float2(cosf(th), sinf(th));
    }
    for (int t = gtid; t < 576; t += gsz) {
        int s = t / 192, rem = t % 192, o = rem / 3, i = rem % 3;
        float fr = freq[t], th = theta[t], sg = sigma[t], f0v = f0[t], th0 = theta0[t];
        float lg  = logf(sg / f0v);
        float a1  = -1.0f / (2.0f * lg * lg);
        float lf0 = logf(f0v);
        float a2  = -1.0f / (2.0f * th0 * th0);
        float lsc = -logf(PI2 * sg * sg);          // log(1/(2pi sg^2))
        int pidx = (s*3 + i)*64 + o;
        pcA[pidx] = make_float4(a1, lf0, a2, th);
        pcB[pidx] = make_float2(fr, lsc);
    }
    for (int t = gtid; t < 64; t += gsz)
        w1f4[t] = make_float4(w1[t*3+0], w1[t*3+1], w1[t*3+2], b1v[t]);
    // W2 B-fragments, t-MAJOR layout (r6): entry u = ((t*2+kc)*2+hsel)*512 +
    // l*8 + j.
    for (int u = gtid; u < 24576; u += gsz) {
        int j = u & 7;
        int l = (u >> 3) & 63;
        int hsel = (u >> 9) & 1;
        int rest = u >> 10;              // t*2 + kc
        int kc = rest & 1;
        int t = rest >> 1;
        int k = kc*32 + (l>>4)*8 + j;
        int c = t*16 + (l & 15);
        float wv = w2[c*64 + k];
        unsigned short hi, lo;
        bf16split(wv, hi, lo);
        w2b[u] = hsel ? lo : hi;
    }
    for (int t = gtid; t < 192; t += gsz) {
        int lo = (int)floorf((fbs[t*2+0] + 1.0f) * 0.5f * 192.0f) - 96;
        int hi = (int)floorf((fbs[t*2+1] + 1.0f) * 0.5f * 192.0f) - 96;
        lo = max(0, min(96, lo));
        hi = max(0, min(96, hi));
        if (hi < lo) hi = lo;
        idx[t*2+0] = lo; idx[t*2+1] = hi;
    }
    if (split) {
        // Stage-2 DFT twiddle B-frags: B_re[k][n], K=384, N=192.
        // offset = ((t*12+kc)*2+half)*512 + lane*8 + j  (shorts)
        unsigned short* e2b = (unsigned short*)(ws + E2B_OFF);
        for (int u = gtid; u < 147456; u += gsz) {
            int j = u & 7;
            int l = (u >> 3) & 63;
            int half = (u >> 9) & 1;
            int rest = u >> 10;              // t*12 + kc
            int kc = rest % 12, t = rest / 12;
            int k = kc*32 + ((l >> 4) << 3) + j;
            int w = k >> 1, comp = k & 1;
            int n = t*16 + (l & 15);
            int ang = (w * n) % 192;
            float th = PI2 * (float)ang / 192.0f;
            float v = comp ? sinf(th) : cosf(th);
            unsigned short hi, lo;
            bf16split(v, hi, lo);
            e2b[u] = half ? lo : hi;
        }
        // Stage-1 DFT twiddle A-frags (fused k_dftm): A[y][h],
        // comp 0 = cos(2pi h y/192), comp 1 = -sin (e^{-i}).
        // Layout: ((yt*2+comp)*6+kc)*2+half)*512 + lane*8 + j; row y =
        // yt*16+(l&15), k h = kc*32+((l>>4)<<3)+j. Lives at T1_OFF.
        unsigned short* e1 = (unsigned short*)(ws + T1_OFF);
        for (int u = gtid; u < 147456; u += gsz) {
            int j = u & 7;
            int l = (u >> 3) & 63;
            int half = (u >> 9) & 1;
            int rest = u >> 10;              // yt*12 + comp*6 + kc
            int kc = rest % 6;
            int comp = (rest / 6) & 1;
            int yt = rest / 12;
            int y = yt*16 + (l & 15);
            int h = kc*32 + ((l >> 4) << 3) + j;
            int ang = (h * y) % 192;
            float th = PI2 * (float)ang / 192.0f;
            float v = comp ? -sinf(th) : cosf(th);
            unsigned short hi, lo;
            bf16split(v, hi, lo);
            e1[u] = half ? lo : hi;
        }
        // IFFT B-frags (K=192, kc 0..5 only) — in d_out.
        // Layout: ((t*6+kc)*2+half)*512 + lane*8 + j  (shorts)
        unsigned short* e2c = (unsigned short*)(outw + E2C_OFF);
        for (int u = gtid; u < 73728; u += gsz) {
            int j = u & 7;
            int l = (u >> 3) & 63;
            int half = (u >> 9) & 1;
            int rest = u >> 10;              // t*6 + kc
            int kc = rest % 6, t = rest / 6;
            int k = kc*32 + ((l >> 4) << 3) + j;
            int w = k >> 1, comp = k & 1;
            int n = t*16 + (l & 15);
            int ang = (w * n) % 192;
            float th = PI2 * (float)ang / 192.0f;
            float v = comp ? sinf(th) : cosf(th);
            unsigned short hi, lo;
            bf16split(v, hi, lo);
            e2c[u] = half ? lo : hi;
        }
    }
}

// ---------------- K1m (split): fused 2D DFT, both stages MFMA ---------------
// Block = (bi, 16-row y-tile). Stage 1: T1[y][w] = sum_h A[y][h] x[h][w],
// A = e^{-2pi i h y/192} from the exact-bf16 e1 table, B = x (hi/lo split on
// the fly), K=192 -> T1 tile straight into LDS Ar[16][194]. Stage 2 is the
// proven k_dft2m body (K=384 re/im over w, B = e2b) + fftshift scatter to Xs.
__global__ __launch_bounds__(256) void k_dftm(const float* x, char* ws) {
    __shared__ __align__(16) float2 Ar[16][194];
    const unsigned short* e1  = (const unsigned short*)(ws + T1_OFF);
    const unsigned short* e2b = (const unsigned short*)(ws + E2B_OFF);
    float2* Xs = (float2*)(ws + XS_OFF);
    int tid = threadIdx.x;
    int bi = blockIdx.x / 12;
    int yt = blockIdx.x % 12;
    int y0 = yt * 16;
    int wave = tid >> 6, lane = tid & 63;
    int ml = lane & 15, qd = lane >> 4;
    const float* xp = x + bi * NPIX;
    union AB { short8 v; unsigned short u[8]; };
    // ---- stage 1 ----
    floatx4 s1re[3], s1im[3];
#pragma unroll
    for (int tt = 0; tt < 3; tt++) {
        s1re[tt] = (floatx4){0.f,0.f,0.f,0.f};
        s1im[tt] = (floatx4){0.f,0.f,0.f,0.f};
    }
#pragma unroll 1
    for (int kc = 0; kc < 6; kc++) {
        const unsigned short* ac = e1 + (((((yt*2 + 0)*6 + kc)*2) << 9) + (lane << 3));
        const unsigned short* as = e1 + (((((yt*2 + 1)*6 + kc)*2) << 9) + (lane << 3));
        short8 ach = *(const short8*)ac;
        short8 acl = *(const short8*)(ac + 512);
        short8 ash = *(const short8*)as;
        short8 asl = *(const short8*)(as + 512);
#pragma unroll
        for (int tt = 0; tt < 3; tt++) {
            int nt = wave*3 + tt;
            AB bh8, bl8;
#pragma unroll
            for (int j = 0; j < 8; j++) {
                int h = kc*32 + qd*8 + j;
                float xv = xp[h*192 + nt*16 + ml];
                bf16split(xv, bh8.u[j], bl8.u[j]);
            }
            floatx4 r = s1re[tt];
            r = __builtin_amdgcn_mfma_f32_16x16x32_bf16(ach, bh8.v, r, 0, 0, 0);
            r = __builtin_amdgcn_mfma_f32_16x16x32_bf16(acl, bh8.v, r, 0, 0, 0);
            r = __builtin_amdgcn_mfma_f32_16x16x32_bf16(ach, bl8.v, r, 0, 0, 0);
            s1re[tt] = r;
            floatx4 q = s1im[tt];
            q = __builtin_amdgcn_mfma_f32_16x16x32_bf16(ash, bh8.v, q, 0, 0, 0);
            q = __builtin_amdgcn_mfma_f32_16x16x32_bf16(asl, bh8.v, q, 0, 0, 0);
            q = __builtin_amdgcn_mfma_f32_16x16x32_bf16(ash, bl8.v, q, 0, 0, 0);
            s1im[tt] = q;
        }
    }
#pragma unroll
    for (int tt = 0; tt < 3; tt++) {
        int w = (wave*3 + tt)*16 + ml;
#pragma unroll
        for (int r = 0; r < 4; r++)
            Ar[qd*4 + r][w] = make_float2(s1re[tt][r], s1im[tt][r]);
    }
    __syncthreads();
    // ---- stage 2 (k_dft2m body) ----
    floatx4 accre[3], accim[3];
#pragma unroll
    for (int tt = 0; tt < 3; tt++) {
        accre[tt] = (floatx4){0.f,0.f,0.f,0.f};
        accim[tt] = (floatx4){0.f,0.f,0.f,0.f};
    }
#pragma unroll 1
    for (int kc = 0; kc < 12; kc++) {
        int wb = kc*16 + qd*4;
        float4 p01 = *(const float4*)&Ar[ml][wb];
        float4 p23 = *(const float4*)&Ar[ml][wb + 2];
        float av[8]  = {p01.x, p01.y, p01.z, p01.w, p23.x, p23.y, p23.z, p23.w};
        float apv[8] = {p01.y, -p01.x, p01.w, -p01.z, p23.y, -p23.x, p23.w, -p23.z};
        AB ah, al, aph, apl;
#pragma unroll
        for (int j = 0; j < 8; j++) {
            bf16split(av[j],  ah.u[j],  al.u[j]);
            bf16split(apv[j], aph.u[j], apl.u[j]);
        }
#pragma unroll
        for (int tt = 0; tt < 3; tt++) {
            int t = wave*3 + tt;
            const unsigned short* bp = e2b + (((t*12 + kc)*2) << 9) + (lane << 3);
            short8 bh = *(const short8*)bp;
            short8 bl = *(const short8*)(bp + 512);
            floatx4 r = accre[tt];
            r = __builtin_amdgcn_mfma_f32_16x16x32_bf16(ah.v,  bh, r, 0, 0, 0);
            r = __builtin_amdgcn_mfma_f32_16x16x32_bf16(al.v,  bh, r, 0, 0, 0);
            r = __builtin_amdgcn_mfma_f32_16x16x32_bf16(ah.v,  bl, r, 0, 0, 0);
            accre[tt] = r;
            floatx4 q = accim[tt];
            q = __builtin_amdgcn_mfma_f32_16x16x32_bf16(aph.v, bh, q, 0, 0, 0);
            q = __builtin_amdgcn_mfma_f32_16x16x32_bf16(apl.v, bh, q, 0, 0, 0);
            q = __builtin_amdgcn_mfma_f32_16x16x32_bf16(aph.v, bl, q, 0, 0, 0);
            accim[tt] = q;
        }
    }
    int b = bi / 3, i = bi % 3;
    int bs = (b + 2) & 3;
    int is = (i + 1) % 3;
    float2* Xp = Xs + (bs*3 + is)*NPIX;
#pragma unroll
    for (int tt = 0; tt < 3; tt++) {
        int kx = (wave*3 + tt)*16 + ml;
        int ks = kx + 96; if (ks >= 192) ks -= 192;
#pragma unroll
        for (int r = 0; r < 4; r++) {
            int y = y0 + qd*4 + r;
            int ys = y + 96; if (ys >= 192) ys -= 192;
            Xp[ys*192 + ks] = make_float2(accre[tt][r], accim[tt][r]);
        }
    }
}

// ---------------- K1 (fallback, fused path): full-h stage-1 DFT -------------
__global__ __launch_bounds__(192) void k_dft1(const float* x, char* ws) {
    __shared__ float2 twsh[192];
    const float2* tw = (const float2*)(ws + TW_OFF);
    float2* t1 = (float2*)(ws + T1_OFF);
    int tid = threadIdx.x;
    twsh[tid] = tw[tid];
    __syncthreads();
    int bi = blockIdx.x;
    int y0 = blockIdx.y * 4;
    int w  = tid;
    const float* xp = x + bi * NPIX;
    float2 acc[4];
#pragma unroll
    for (int d = 0; d < 4; d++) acc[d] = make_float2(0.f, 0.f);
    for (int h = 0; h < 192; h++) {
        float xv = xp[h*192 + w];
        int m = (h * y0) % 192;
#pragma unroll
        for (int d = 0; d < 4; d++) {
            float2 e = twsh[m];
            acc[d].x += xv * e.x;
            acc[d].y -= xv * e.y;
            m += h; if (m >= 192) m -= 192;
        }
    }
    float2* op = t1 + bi * NPIX;
#pragma unroll
    for (int d = 0; d < 4; d++) op[(y0 + d)*192 + w] = acc[d];
}

// ---------------- K2 (fallback, fused path): scalar stage-2 DFT -------------
__global__ __launch_bounds__(192) void k_dft2(char* ws) {
    __shared__ float2 twsh[192];
    __shared__ float2 row[192];
    const float2* tw = (const float2*)(ws + TW_OFF);
    const float2* t1a = (const float2*)(ws + T1_OFF);
    float2* Xs = (float2*)(ws + XS_OFF);
    int tid = threadIdx.x;
    int bi = blockIdx.x, y = blockIdx.y;
    twsh[tid] = tw[tid];
    row[tid] = t1a[bi*NPIX + y*192 + tid];
    __syncthreads();
    int kx = tid;
    float2 st = twsh[kx];
    float2 acc = make_float2(0.f, 0.f);
#pragma unroll 1
    for (int w0 = 0; w0 < 192; w0 += 32) {
        float2 e = twsh[(w0 * kx) % 192];
#pragma unroll
        for (int w = 0; w < 32; w++) {
            float2 t = row[w0 + w];
            acc.x += t.x*e.x + t.y*e.y;          // t * conj(e)
            acc.y += t.y*e.x - t.x*e.y;
            float ex = e.x*st.x - e.y*st.y;
            e.y = e.x*st.y + e.y*st.x;
            e.x = ex;
        }
    }
    int b = bi / 3, i = bi % 3;
    int bs = (b + 2) & 3;
    int is = (i + 1) % 3;
    int ys = y + 96;  if (ys >= 192) ys -= 192;
    int ks = kx + 96; if (ks >= 192) ks -= 192;
    Xs[(bs*3 + is)*NPIX + ys*192 + ks] = acc;
}

// ---------------- K3: MFMA SYRK for BN stats: M2 = H1^T H1, m1 = sum(H1) ----
__global__ __launch_bounds__(256) void k_stats(char* ws) {
    __shared__ float magL[192];                    // [s][i] at s*3+i
    __shared__ float4 w1L[64];
    __shared__ float m1L[64];
    __shared__ __align__(16) unsigned short fragH[512*8];  // z*8, z=(kc*4+cb)*64+l
    __shared__ __align__(16) unsigned short fragL[512*8];
    const float2* Xs = (const float2*)(ws + XS_OFF);
    float* M2 = (float*)(ws + M2_OFF);
    int tid = threadIdx.x;
    int wave = tid >> 6, lane = tid & 63;
    if (tid < 64) { w1L[tid] = ((const float4*)(ws + W1F4_OFF))[tid]; m1L[tid] = 0.f; }
    __syncthreads();
    int cch = wave*16 + (lane & 15);               // this thread's channel
    float4 wf = w1L[cch];
    float msum = 0.f;
    floatx4 acc[4];
#pragma unroll
    for (int nb = 0; nb < 4; nb++) acc[nb] = (floatx4){0.f, 0.f, 0.f, 0.f};
    union AB { short8 v; unsigned short u[8]; };
#pragma unroll 1
    for (int it = 0; it < 2; it++) {
        int tile = blockIdx.x * 2 + it;            // 1152*2 = 2304 tiles
        int S0 = tile * 64;
        int b = S0 / NPIX;                         // NPIX%64==0 -> const per tile
        int p0 = S0 - b*NPIX;
        if (tid < 192) {
            int i = tid >> 6, s = tid & 63;
            float2 v = Xs[(b*3 + i)*NPIX + p0 + s];
            magL[s*3 + i] = sqrtf(v.x*v.x + v.y*v.y);
        }
        __syncthreads();
#pragma unroll
        for (int kc = 0; kc < 2; kc++) {
            AB h8, l8;
#pragma unroll
            for (int j = 0; j < 8; j++) {
                int s = kc*32 + (lane>>4)*8 + j;
                float mg0 = magL[s*3], mg1 = magL[s*3+1], mg2 = magL[s*3+2];
                float hv = fmaxf(wf.w + wf.x*mg0 + wf.y*mg1 + wf.z*mg2, 0.f);
                msum += hv;
                bf16split(hv, h8.u[j], l8.u[j]);
            }
            int z = (kc*4 + wave)*64 + lane;
            *(short8*)&fragH[z*8] = h8.v;
            *(short8*)&fragL[z*8] = l8.v;
        }
        __syncthreads();
        short8 Ah0 = *(const short8*)&fragH[((0*4+wave)*64 + lane)*8];
        short8 Ah1 = *(const short8*)&fragH[((1*4+wave)*64 + lane)*8];
        short8 Al0 = *(const short8*)&fragL[((0*4+wave)*64 + lane)*8];
        short8 Al1 = *(const short8*)&fragL[((1*4+wave)*64 + lane)*8];
#pragma unroll
        for (int nb = 0; nb < 4; nb++) {
            short8 Bh0 = *(const short8*)&fragH[((0*4+nb)*64 + lane)*8];
            short8 Bh1 = *(const short8*)&fragH[((1*4+nb)*64 + lane)*8];
            short8 Bl0 = *(const short8*)&fragL[((0*4+nb)*64 + lane)*8];
            short8 Bl1 = *(const short8*)&fragL[((1*4+nb)*64 + lane)*8];
            floatx4 a = acc[nb];
            a = __builtin_amdgcn_mfma_f32_16x16x32_bf16(Ah0, Bh0, a, 0, 0, 0);
            a = __builtin_amdgcn_mfma_f32_16x16x32_bf16(Al0, Bh0, a, 0, 0, 0);
            a = __builtin_amdgcn_mfma_f32_16x16x32_bf16(Ah0, Bl0, a, 0, 0, 0);
            a = __builtin_amdgcn_mfma_f32_16x16x32_bf16(Ah1, Bh1, a, 0, 0, 0);
            a = __builtin_amdgcn_mfma_f32_16x16x32_bf16(Al1, Bh1, a, 0, 0, 0);
            a = __builtin_amdgcn_mfma_f32_16x16x32_bf16(Ah1, Bl1, a, 0, 0, 0);
            acc[nb] = a;
        }
        __syncthreads();
    }
#pragma unroll
    for (int nb = 0; nb < 4; nb++)
#pragma unroll
        for (int r = 0; r < 4; r++) {
            int row = wave*16 + (lane>>4)*4 + r;
            int col = nb*16 + (lane & 15);
            atomicAdd(&M2[row*64 + col], acc[nb][r]);
        }
    atomicAdd(&m1L[cch], msum);
    __syncthreads();
    if (tid < 64) atomicAdd(&M2[4096 + tid], m1L[tid]);
}

// ---------------- K4: BN scale/shift, one block per channel -----------------
__global__ __launch_bounds__(64) void k_bn(const float* w2, const float* bnw,
                                           const float* bnb, char* ws) {
    const float* M2 = (const float*)(ws + M2_OFF);
    const float* m1 = M2 + 4096;
    float* bnsc = (float*)(ws + BN_OFF);
    float* bnsh = bnsc + 192;
    int c = blockIdx.x;
    int jj = threadIdx.x;
    const float* row = w2 + c*64;
    float rj = row[jj];
    float inner = 0.f;
    const float* m2r = M2 + jj*64;
    for (int k = 0; k < 64; k++) inner += row[k] * m2r[k];
    float qpart = rj * inner;
    float dpart = rj * m1[jj];
#pragma unroll
    for (int sh = 32; sh >= 1; sh >>= 1) {
        qpart += __shfl_xor(qpart, sh);
        dpart += __shfl_xor(dpart, sh);
    }
    if (jj == 0) {
        const float invN = 1.0f / 147456.0f;
        float d = dpart * invN;
        float qv = qpart * invN;
        float var = qv - d*d;
        float rstd = rsqrtf(var + 1e-5f);
        float scale = bnw[c] * rstd;
        bnsc[c] = scale;
        bnsh[c] = bnb[c] - d * scale;
    }
}

// ---------------- K5: MFMA attention + gabor -> A_tot (online softmax) ------
__global__ __launch_bounds__(256) void k_attn(char* ws) {
    __shared__ __align__(16) float4 pcAL[576];
    __shared__ float2 pcBL[576];
    __shared__ float4 w1L[64];
    const float2* Xs = (const float2*)(ws + XS_OFF);
    const float* bnA = (const float*)(ws + BN_OFF);   // [0..192) scale, [192..384) shift
    const char* W2G = (const char*)(ws + W2B_OFF);
    float2* Ah = (float2*)(ws + AH_OFF);
    int tid = threadIdx.x;
    {
        const float4* pcA4 = (const float4*)(ws + PCA_OFF);
        const float2* pcB2 = (const float2*)(ws + PCB_OFF);
        for (int u = tid; u < 576; u += 256) {
            pcAL[u] = pcA4[u];
            pcBL[u] = pcB2[u];
        }
        if (tid < 64) w1L[tid] = ((const float4*)(ws + W1F4_OFF))[tid];
    }
    __syncthreads();
    int wave = tid >> 6, lane = tid & 63;
    int cl = lane & 15, q = lane >> 4;
    int g = blockIdx.x * 4 + wave;
    int pix0 = g * 4;

    union AB { short8 v; unsigned short u[8]; };
    int pb = pix0 + (cl >> 2), bb = cl & 3;
    float2 q0 = Xs[(bb*3+0)*NPIX + pb];
    float2 q1 = Xs[(bb*3+1)*NPIX + pb];
    float2 q2 = Xs[(bb*3+2)*NPIX + pb];
    float mg0 = sqrtf(q0.x*q0.x + q0.y*q0.y);
    float mg1 = sqrtf(q1.x*q1.x + q1.y*q1.y);
    float mg2 = sqrtf(q2.x*q2.x + q2.y*q2.y);
    AB ah[2], al[2];
#pragma unroll
    for (int kc = 0; kc < 2; kc++)
#pragma unroll
        for (int j = 0; j < 8; j++) {
            int k = kc*32 + q*8 + j;
            float4 wf = w1L[k];
            float hv = fmaxf(wf.w + wf.x*mg0 + wf.y*mg1 + wf.z*mg2, 0.f);
            bf16split(hv, ah[kc].u[j], al[kc].u[j]);
        }
    int pixE = pix0 + q;
    int hh = pixE / 192, ww = pixE - hh*192;
    float yy = -1.0f + (float)hh * (2.0f/191.0f);
    float xx = -1.0f + (float)ww * (2.0f/191.0f);
    float rr = sqrtf(xx*xx + yy*yy + 1e-6f);
    float lr = __logf(rr);
    float phi = atan2f(yy, xx);
    float sm0 = 0.f, sm1 = 0.f, sm2 = 0.f, sm3 = 0.f;
    float Wr[4][3];
#pragma unroll
    for (int r = 0; r < 4; r++) { Wr[r][0] = 0.f; Wr[r][1] = 0.f; Wr[r][2] = 0.f; }
#pragma unroll 2
    for (int t = 0; t < 12; t++) {
        floatx4 a = {0.f, 0.f, 0.f, 0.f};
#pragma unroll
        for (int kc = 0; kc < 2; kc++) {
            int ob = (((t*2 + kc)*2)*64 + lane)*16;      // t-major (r6)
            short8 bh = *(const short8*)(W2G + ob);
            short8 bl = *(const short8*)(W2G + ob + 1024);
            a = __builtin_amdgcn_mfma_f32_16x16x32_bf16(ah[kc].v, bh, a, 0, 0, 0);
            a = __builtin_amdgcn_mfma_f32_16x16x32_bf16(al[kc].v, bh, a, 0, 0, 0);
            a = __builtin_amdgcn_mfma_f32_16x16x32_bf16(ah[kc].v, bl, a, 0, 0, 0);
        }
        int c = t*16 + cl;
        float sc_ = bnA[c], sh_ = bnA[192 + c];
        float e0 = __expf(a[0]*sc_ + sh_);
        float e1 = __expf(a[1]*sc_ + sh_);
        float e2 = __expf(a[2]*sc_ + sh_);
        float e3 = __expf(a[3]*sc_ + sh_);
        sm0 += e0; sm1 += e1; sm2 += e2; sm3 += e3;
        int sB = c >> 6, o = c & 63;
#pragma unroll
        for (int i = 0; i < 3; i++) {
            int pidx = (sB*3 + i)*64 + o;
            float4 pa = pcAL[pidx];
            float2 pbv = pcBL[pidx];
            float dl = lr - pa.y, dp = phi - pa.w;
            float gv = __expf(pa.x*dl*dl + pa.z*dp*dp + pbv.y) * __cosf(pbv.x*rr);
            Wr[0][i] += e0*gv; Wr[1][i] += e1*gv;
            Wr[2][i] += e2*gv; Wr[3][i] += e3*gv;
        }
    }
#pragma unroll
    for (int sh = 1; sh < 16; sh <<= 1) {
        sm0 += __shfl_xor(sm0, sh); sm1 += __shfl_xor(sm1, sh);
        sm2 += __shfl_xor(sm2, sh); sm3 += __shfl_xor(sm3, sh);
    }
    float inv0 = 1.0f/sm0, inv1 = 1.0f/sm1, inv2 = 1.0f/sm2, inv3 = 1.0f/sm3;
    float are = 0.f, aim = 0.f;
#pragma unroll
    for (int i = 0; i < 3; i++) {
        float2 x0 = Xs[(0*3+i)*NPIX + pixE];
        float2 x1 = Xs[(1*3+i)*NPIX + pixE];
        float2 x2 = Xs[(2*3+i)*NPIX + pixE];
        float2 x3 = Xs[(3*3+i)*NPIX + pixE];
        float w0v = Wr[0][i]*inv0, w1v = Wr[1][i]*inv1;
        float w2v = Wr[2][i]*inv2, w3v = Wr[3][i]*inv3;
        are += w0v*x0.x + w1v*x1.x + w2v*x2.x + w3v*x3.x;
        aim += w0v*x0.y + w1v*x1.y + w2v*x2.y + w3v*x3.y;
    }
#pragma unroll
    for (int sh = 1; sh < 16; sh <<= 1) {
        are += __shfl_xor(are, sh);
        aim += __shfl_xor(aim, sh);
    }
    if (cl == 0) {
        int hs = hh + 96; if (hs >= 192) hs -= 192;
        int wsx = ww + 96; if (wsx >= 192) wsx -= 192;
        Ah[hs*192 + wsx] = make_float2(are, aim);
    }
}

// ---------------- K6a-1: h-prefix column DFT table (split path) -------------
// Ph[m-1][w][y] = sum_{h<m} Ah[h][w] e^{+2pi i h y/192}, m=1..96, w<96, y<192.
// r8: grid (96 w, 3 y-thirds) x 64 threads = 288 blocks WITH the r4 LDS
// staging of the Ah column (alias-serialization fix).
__global__ __launch_bounds__(64) void k_phpre(char* ws, char* outw) {
    __shared__ float2 AhL[96];
    const float2* tw  = (const float2*)(ws + TW_OFF);
    const float2* Ahp = (const float2*)(ws + AH_OFF);
    float2* Ph = (float2*)outw;
    int tid = threadIdx.x;
    int y = blockIdx.y * 64 + tid;       // 0..191
    int w = blockIdx.x;                  // 0..95
    for (int u = tid; u < 96; u += 64) AhL[u] = Ahp[u*192 + w];
    __syncthreads();
    float2 step = tw[y];
    float ex = 1.f, ey = 0.f;            // e^{+2pi i h y/192}, h=0
    float ax = 0.f, ay = 0.f;
    for (int h = 0; h < 96; h++) {
        float2 a = AhL[h];
        ax += a.x*ex - a.y*ey;
        ay += a.x*ey + a.y*ex;
        Ph[(h*96 + w)*192 + y] = make_float2(ax, ay);
        float t = ex*step.x - ey*step.y;
        ey = ex*step.y + ey*step.x;
        ex = t;
    }
}

// ---------------- K6a-2: masked IDFT as MFMA matmul (split path) ------------
__global__ __launch_bounds__(256) void k_ifftm(char* ws, char* outw) {
    __shared__ __align__(16) unsigned short AhiL[16*200];  // [yy][k], pad 192->200
    __shared__ __align__(16) unsigned short AloL[16*200];
    __shared__ int iL[3], iH[3];
    const float2* Ph = (const float2*)outw;
    const unsigned short* e2c = (const unsigned short*)(outw + E2C_OFF);
    const int* idx = (const int*)(ws + IDX_OFF);
    float* xf = (float*)(ws + XF_OFF);
    int tid = threadIdx.x;
    int o  = blockIdx.x / 12;
    int ys = blockIdx.x % 12;            // 16-row slab: rows ys*16 .. +15
    int op = (o + 32) & 63;              // ifftshift on the channel axis
    if (tid < 3) { iL[tid] = idx[(op*3 + tid)*2]; iH[tid] = idx[(op*3 + tid)*2 + 1]; }
    __syncthreads();
    // ---- gather Stot -> A' bf16 hi/lo fragments in LDS (1536 entries) ----
    for (int u = tid; u < 1536; u += 256) {
        int w = u >> 4, yy = u & 15;
        int y = ys*16 + yy;
        float sr = 0.f, si = 0.f;
#pragma unroll
        for (int i = 0; i < 3; i++) {
            int lo = iL[i], hi = iH[i];
            if (w >= lo && w < hi) {
                float2 a = Ph[((hi-1)*96 + w)*192 + y];
                sr += a.x; si += a.y;
                if (lo > 0) {
                    float2 b2 = Ph[((lo-1)*96 + w)*192 + y];
                    sr -= b2.x; si -= b2.y;
                }
            }
        }
        unsigned short rh, rl, ih, il;
        bf16split(sr, rh, rl);
        bf16split(-si, ih, il);
        *(unsigned*)&AhiL[yy*200 + 2*w] = (unsigned)rh | ((unsigned)ih << 16);
        *(unsigned*)&AloL[yy*200 + 2*w] = (unsigned)rl | ((unsigned)il << 16);
    }
    __syncthreads();
    // ---- MFMA: M=16 (1 m-tile), N=192 (12 n-tiles / 4 waves), K=192 ----
    int wave = tid >> 6, lane = tid & 63;
    int ml = lane & 15, qd = lane >> 4;
    const float s = 1.0f / 36864.0f;
#pragma unroll 1
    for (int ntl = 0; ntl < 3; ntl++) {
        int nt = wave*3 + ntl;
        floatx4 acc = (floatx4){0.f,0.f,0.f,0.f};
#pragma unroll
        for (int kc = 0; kc < 6; kc++) {
            const unsigned short* bp = e2c + ((nt*6 + kc) << 10) + (lane << 3);
            short8 bh = *(const short8*)bp;
            short8 bl = *(const short8*)(bp + 512);
            int ka = kc*32 + qd*8;
            short8 ah = *(const short8*)&AhiL[ml*200 + ka];
            short8 al = *(const short8*)&AloL[ml*200 + ka];
            acc = __builtin_amdgcn_mfma_f32_16x16x32_bf16(ah, bh, acc, 0, 0, 0);
            acc = __builtin_amdgcn_mfma_f32_16x16x32_bf16(al, bh, acc, 0, 0, 0);
            acc = __builtin_amdgcn_mfma_f32_16x16x32_bf16(ah, bl, acc, 0, 0, 0);
        }
#pragma unroll
        for (int r = 0; r < 4; r++) {
            int y = ys*16 + qd*4 + r;
            int x = nt*16 + ml;
            xf[o*NPIX + y*192 + x] = acc[r] * s;
        }
    }
}

// ---------------- K6b: 3x3 conv (sgpr weights) + mix (split path) -----------
// r9: ALIAS FIX. The o-loop was load-xf -> store-out -> load-xf ...; xf (ws)
// and out (d_out) had no alias info, so the compiler could not hoist the next
// xf load above the previous out store -> 16 serialized LLC-latency loads per
// thread (44.7us, VALUBusy 22%, HBM 13%). Preload all 16 xf values BEFORE the
// store loop + __restrict__ everywhere. Same math, same order.
__global__ __launch_bounds__(192) void k_conv(const float* __restrict__ x,
                                              const float* __restrict__ convw,
                                              const float* __restrict__ mixp,
                                              const float* __restrict__ xf,
                                              float* __restrict__ out) {
    int col = threadIdx.x;
    int y = blockIdx.x;
    int b = blockIdx.y;
    int o0 = blockIdx.z * 16;
    float xv[27];
#pragma unroll
    for (int i = 0; i < 3; i++)
#pragma unroll
        for (int dy = 0; dy < 3; dy++)
#pragma unroll
            for (int dx = 0; dx < 3; dx++) {
                int yq = y + dy - 1, xq = col + dx - 1;
                bool ok = (yq >= 0) & (yq < 192) & (xq >= 0) & (xq < 192);
                xv[(i*3 + dy)*3 + dx] = ok ? x[(b*3+i)*NPIX + yq*192 + xq] : 0.f;
            }
    float xfv[16];
#pragma unroll
    for (int oo = 0; oo < 16; oo++)
        xfv[oo] = xf[(o0 + oo)*NPIX + y*192 + col];
    float mixv = mixp[0];
    float onem = 1.0f - mixv;
#pragma unroll
    for (int oo = 0; oo < 16; oo++) {
        int o = o0 + oo;
        float s = 0.f;
#pragma unroll
        for (int c = 0; c < 27; c++) s += xv[c] * convw[o*27 + c];
        out[((b*64 + o)*192 + y)*192 + col] = mixv*xfv[oo] + onem*s;
    }
}

// ---------------- K6 (fallback): fused IDFT + conv + mix --------------------
__global__ __launch_bounds__(192) void k_final(const float* x, const float* convw,
                                               const float* mixp, float* out, char* ws) {
    __shared__ float2 twsh[192];
    __shared__ float2 Ssh[3][96];
    __shared__ float cwsh[27];
    __shared__ int iL[3], iH[3];
    const float2* tw = (const float2*)(ws + TW_OFF);
    const int* idx = (const int*)(ws + IDX_OFF);
    const float2* Ah = (const float2*)(ws + AH_OFF);
    int tid = threadIdx.x;
    int y = blockIdx.x;
    int o = blockIdx.y;
    int op = (o + 32) & 63;
    twsh[tid] = tw[tid];
    if (tid < 27) cwsh[tid] = convw[o*27 + tid];
    if (tid < 3) { iL[tid] = idx[(op*3 + tid)*2]; iH[tid] = idx[(op*3 + tid)*2 + 1]; }
    __syncthreads();
    int l0 = iL[0], u0 = iH[0], l1 = iL[1], u1 = iH[1], l2 = iL[2], u2 = iH[2];
    int n0 = u0 - l0, n1 = u1 - l1, n2 = u2 - l2;
    int p1 = n0 + n1, T = p1 + n2;
    for (int t = tid; t < T; t += 192) {
        int i, off, lo, hi;
        if (t < n0)      { i = 0; off = t;      lo = l0; hi = u0; }
        else if (t < p1) { i = 1; off = t - n0; lo = l1; hi = u1; }
        else             { i = 2; off = t - p1; lo = l2; hi = u2; }
        int wq = lo + off;
        float sx = 0.f, sy = 0.f;
        int m = (lo * y) % 192;
        for (int hq = lo; hq < hi; hq++) {
            float2 a = Ah[hq*192 + wq];
            float2 e = twsh[m];
            sx += a.x*e.x - a.y*e.y;
            sy += a.x*e.y + a.y*e.x;
            m += y; if (m >= 192) m -= 192;
        }
        Ssh[i][off] = make_float2(sx, sy);
    }
    __syncthreads();
    int col = tid;
    float accre = 0.f;
#pragma unroll
    for (int i = 0; i < 3; i++) {
        int lo = iL[i];
        int wi = iH[i] - lo;
        int m = (lo * col) % 192;
        for (int off = 0; off < wi; off++) {
            float2 S = Ssh[i][off];
            float2 e = twsh[m];
            accre += S.x*e.x - S.y*e.y;
            m += col; if (m >= 192) m -= 192;
        }
    }
    float xfv = accre * (1.0f / 36864.0f);
    float mixv = mixp[0];
    float onem = 1.0f - mixv;
#pragma unroll
    for (int b = 0; b < 4; b++) {
        float s = 0.f;
#pragma unroll
        for (int i = 0; i < 3; i++) {
            const float* xp = x + (b*3 + i)*NPIX;
#pragma unroll
            for (int dy = -1; dy <= 1; dy++) {
                int yq = y + dy;
                if (yq < 0 || yq >= 192) continue;
                const float* rowp = xp + yq*192;
#pragma unroll
                for (int dx = -1; dx <= 1; dx++) {
                    int xq = col + dx;
                    if (xq < 0 || xq >= 192) continue;
                    s += rowp[xq] * cwsh[i*9 + (dy+1)*3 + (dx+1)];
                }
            }
        }
        out[((b*64 + o)*192 + y)*192 + col] = mixv*xfv + onem*s;
    }
}

extern "C" void kernel_launch(void* const* d_in, const int* in_sizes, int n_in,
                              void* d_out, int out_size, void* d_ws, size_t ws_size,
                              hipStream_t stream) {
    const float* x      = (const float*)d_in[0];
    const float* freq   = (const float*)d_in[1];
    const float* theta  = (const float*)d_in[2];
    const float* sigma  = (const float*)d_in[3];
    const float* f0     = (const float*)d_in[4];
    const float* theta0 = (const float*)d_in[5];
    const float* aw1    = (const float*)d_in[6];
    const float* ab1    = (const float*)d_in[7];
    const float* aw2    = (const float*)d_in[8];
    // d_in[9] = attn_b2: cancelled exactly by BN mean-subtraction, unused
    const float* bnw    = (const float*)d_in[10];
    const float* bnb    = (const float*)d_in[11];
    const float* mixp   = (const float*)d_in[12];
    const float* convw  = (const float*)d_in[13];
    const float* fbs    = (const float*)d_in[14];
    float* out = (float*)d_out;
    char* ws = (char*)d_ws;
    char* outc = (char*)d_out;
    if (ws_size < (size_t)WS_FUSED) return;
    // out is the full [4,64,192,192] f32 tensor (37.7 MB) -> >= 14.3 MB scratch
    // need under EITHER unit of out_size (bytes or elements).
    int split = (ws_size >= (size_t)WS_SPLIT) && (out_size >= OUT_MIN_ELEMS);

    hipMemsetAsync(ws + M2_OFF, 0, 16640, stream);
    k_pre  <<<192, 256, 0, stream>>>(freq, theta, sigma, f0, theta0, fbs,
                                     aw1, ab1, aw2, ws, outc, split);
    if (split) {
        k_dftm <<<144, 256, 0, stream>>>(x, ws);
    } else {
        k_dft1 <<<dim3(12, 48), 192, 0, stream>>>(x, ws);
        k_dft2 <<<dim3(12, 192), 192, 0, stream>>>(ws);
    }
    k_stats<<<1152, 256, 0, stream>>>(ws);
    k_bn   <<<192, 64, 0, stream>>>(aw2, bnw, bnb, ws);
    k_attn <<<2304, 256, 0, stream>>>(ws);
    if (split) {
        k_phpre<<<dim3(96, 3), 64, 0, stream>>>(ws, outc);
        k_ifftm<<<768, 256, 0, stream>>>(ws, outc);
        k_conv <<<dim3(192, 4, 4), 192, 0, stream>>>(x, convw, mixp,
                                                     (const float*)(ws + XF_OFF), out);
    } else {
        k_final<<<dim3(192, 64), 192, 0, stream>>>(x, convw, mixp, out, ws);
    }
}